// Round 12
// baseline (698.001 us; speedup 1.0000x reference)
//
#include <hip/hip_runtime.h>
#include <stdint.h>

// Fused transformer block on MI355X (gfx950), fp16 MFMA pipeline.
// Plan A (ws >= 240 MiB): gemm8x — m201-faithful 8-phase schedule (r12):
//   256x256 tile, BK=64, 8 waves (2Mx4N, per-wave 128x64), 2 LDS buffers
//   (buf0=even K-tiles, buf1=odd; 128 KiB), XOR bank swizzle.
//   Phase = { ds_read this quadrant's frags (PRE-barrier, overlaps other
//   waves' MFMA of prev phase) ; stage ONE half-tile (2 gload_lds) ;
//   [gate only at p3/p7: vmcnt(2), last-iter vmcnt(0)] ; s_barrier ;
//   lgkmcnt(0)+sched_barrier ; setprio(1) 16 MFMA setprio(0) ; s_barrier }.
//   Stage map (iter i, ta=2i, tb=2i+1): p0:B0(tb) p1:B1(tb) p2:A1(tb)
//   p3:A0(ta+2) p4:B0(ta+2) p5:B1(ta+2) p6:A1(ta+2) p7:A0(tb+2).
//   Gate ledger: gate@p3-end retires tb (A0@p7prev,B0@p0,B1@p1,A1@p2;
//   outstanding = p3's 2 -> vmcnt(2)); gate@p7-end retires ta+2 (p3..p6;
//   outstanding = p7's 2 -> vmcnt(2)). Last iter: p3 gate vmcnt(0), no p7
//   gate. Prologue: 10 loads (t0 full + A0(t1)), vmcnt(2), barrier.
//   Write-safety: every region re-staged >=1 barrier after its last
//   lgkm-drained read.
// Attention: 2 chunks of 1024 Q-rows, fp16 scores, softmax in place.
// Plans B/C keep the round-3-verified m97-structure gemm_bt.

#define DEVI __device__ __forceinline__

typedef uint16_t u16;
typedef _Float16 f16x8 __attribute__((ext_vector_type(8)));
typedef float f32x4 __attribute__((ext_vector_type(4)));

DEVI u16 f2h(float f) {
  union { _Float16 h; u16 u; } v;
  v.h = (_Float16)f;
  return v.u;
}
DEVI float h2f(u16 x) {
  union { _Float16 h; u16 u; } v;
  v.u = x;
  return (float)v.h;
}

DEVI void gload_lds16(const void* g, void* lds) {
  __builtin_amdgcn_global_load_lds(
      (const __attribute__((address_space(1))) void*)g,
      (__attribute__((address_space(3))) void*)lds, 16, 0, 0);
}

#define LGKM0 do { asm volatile("s_waitcnt lgkmcnt(0)" ::: "memory"); \
                   __builtin_amdgcn_sched_barrier(0); } while (0)

// ================================================================ gemm8x
// C[M,N] = A[M,K] * B^T, B row-major [N,K] (fp16). 512 thr = 8 waves (2Mx4N),
// per-wave 128x64 via 8x4 16x16x32 fragments. Tile 256x256, BK=64.
// EPI: 0 fp16; 2 fp32 bias+relu+residual; 3 fp16 V-transposed store.
template <int EPI>
__global__ __launch_bounds__(512, 2) void gemm8x(
    const u16* __restrict__ A, const u16* __restrict__ B, void* __restrict__ C,
    int K, int lda, int ldb, int ldc,
    long aZ, long bZ, long cZ,
    const float* __restrict__ bias, const float* __restrict__ xres)
{
  __shared__ u16 lds[2 * 32768];  // per buf: A [256][64] @0, B [256][64] @32768
  char* ldsB = (char*)lds;
  const int tid = threadIdx.x;
  const int bz = blockIdx.z;

  // XCD-aware swizzle (gx*gy % 8 == 0 for all grids used)
  const int gx = gridDim.x;
  int fl = blockIdx.y * gx + blockIdx.x;
  const int cpx = (gx * gridDim.y) >> 3;
  fl = (fl & 7) * cpx + (fl >> 3);
  const int bx = fl % gx, by = fl / gx;

  const u16* Ab = A + (long)bz * aZ + (long)(by * 256) * lda;
  const u16* Bb = B + (long)bz * bZ + (long)(bx * 256) * ldb;

  const int wid = tid >> 6, lane = tid & 63;
  const int wm = wid >> 2, wn = wid & 3;  // 2M x 4N
  const int l15 = lane & 15;

  // staging maps (half h, chunk j): wave-uniform LDS dest + inverse-swizzled
  // per-lane global source. A-half h = rows [64h,+64) u [128+64h,+64);
  // B-half h = rows with bit5==h within each 64-row wn group.
  int aBase[2][2]; long aoff[2][2];
  int bBase[2][2]; long boff[2][2];
#pragma unroll
  for (int h = 0; h < 2; ++h) {
#pragma unroll
    for (int j = 0; j < 2; ++j) {
      const int s = wid * 2 + j;  // 0..15
      int rs = (s < 8) ? (64 * h + s * 8) : (128 + 64 * h + (s - 8) * 8);
      aBase[h][j] = rs * 128;
      {
        const int d = rs * 128 + lane * 16;
        const int dl = d ^ (((d >> 7) & 7) << 4);
        aoff[h][j] = (long)(dl >> 7) * (lda * 2) + (dl & 127);
      }
      rs = 64 * (s >> 2) + 32 * h + (s & 3) * 8;
      bBase[h][j] = 32768 + rs * 128;
      {
        const int d = rs * 128 + lane * 16;
        const int dl = d ^ (((d >> 7) & 7) << 4);
        boff[h][j] = (long)(dl >> 7) * (ldb * 2) + (dl & 127);
      }
    }
  }

  const int swz = (lane & 7) << 4;
  const int ko0 = ((lane >> 4) * 16) ^ swz;
  const int ko1 = (64 + (lane >> 4) * 16) ^ swz;

  f32x4 acc[8][4] = {};

  auto STAGE_A = [&](int t, int h) {
    char* dst = ldsB + (t & 1) * 65536;
    const long kB = (long)t * 128;
#pragma unroll
    for (int j = 0; j < 2; ++j)
      gload_lds16((const char*)Ab + aoff[h][j] + kB, dst + aBase[h][j]);
  };
  auto STAGE_B = [&](int t, int h) {
    char* dst = ldsB + (t & 1) * 65536;
    const long kB = (long)t * 128;
#pragma unroll
    for (int j = 0; j < 2; ++j)
      gload_lds16((const char*)Bb + boff[h][j] + kB, dst + bBase[h][j]);
  };
  auto RD_A = [&](const char* base, int mh, f16x8* dst) {
#pragma unroll
    for (int m = 0; m < 4; ++m) {
      const char* r = base + (wm * 128 + (mh * 4 + m) * 16 + l15) * 128;
      dst[2 * m] = *(const f16x8*)(r + ko0);
      dst[2 * m + 1] = *(const f16x8*)(r + ko1);
    }
  };
  auto RD_B = [&](const char* base, int nh, f16x8* dst) {
#pragma unroll
    for (int n = 0; n < 2; ++n) {
      const char* r = base + 32768 + (wn * 64 + (nh * 2 + n) * 16 + l15) * 128;
      dst[2 * n] = *(const f16x8*)(r + ko0);
      dst[2 * n + 1] = *(const f16x8*)(r + ko1);
    }
  };

  const int NT = K >> 6;       // even (K multiple of 128)
  const int NI = NT >> 1;
  const char* buf0 = ldsB;
  const char* buf1 = ldsB + 65536;

  // prologue: t0 full + A0(t1) = 10 loads; retire t0 (leave 2); barrier
  STAGE_A(0, 0); STAGE_B(0, 0); STAGE_B(0, 1); STAGE_A(0, 1);
  STAGE_A(1, 0);
  asm volatile("s_waitcnt vmcnt(2)" ::: "memory");
  __builtin_amdgcn_s_barrier();

  for (int i = 0; i < NI; ++i) {
    const bool last = (i + 1 == NI);
    const int ta = 2 * i, tb = 2 * i + 1;
    f16x8 af[8], b0v[4], b1v[4];

    // ---- p0: quad(0,0) ta
    RD_A(buf0, 0, af); RD_B(buf0, 0, b0v);
    STAGE_B(tb, 0);
    __builtin_amdgcn_s_barrier();
    LGKM0;
    __builtin_amdgcn_s_setprio(1);
#pragma unroll
    for (int ks = 0; ks < 2; ++ks)
#pragma unroll
      for (int m = 0; m < 4; ++m)
#pragma unroll
        for (int n = 0; n < 2; ++n)
          acc[m][n] = __builtin_amdgcn_mfma_f32_16x16x32_f16(
              af[2 * m + ks], b0v[2 * n + ks], acc[m][n], 0, 0, 0);
    __builtin_amdgcn_s_setprio(0);
    __builtin_amdgcn_s_barrier();

    // ---- p1: quad(0,1) ta
    RD_B(buf0, 1, b1v);
    STAGE_B(tb, 1);
    __builtin_amdgcn_s_barrier();
    LGKM0;
    __builtin_amdgcn_s_setprio(1);
#pragma unroll
    for (int ks = 0; ks < 2; ++ks)
#pragma unroll
      for (int m = 0; m < 4; ++m)
#pragma unroll
        for (int n = 0; n < 2; ++n)
          acc[m][n + 2] = __builtin_amdgcn_mfma_f32_16x16x32_f16(
              af[2 * m + ks], b1v[2 * n + ks], acc[m][n + 2], 0, 0, 0);
    __builtin_amdgcn_s_setprio(0);
    __builtin_amdgcn_s_barrier();

    // ---- p2: quad(1,0) ta
    RD_A(buf0, 1, af);
    STAGE_A(tb, 1);
    __builtin_amdgcn_s_barrier();
    LGKM0;
    __builtin_amdgcn_s_setprio(1);
#pragma unroll
    for (int ks = 0; ks < 2; ++ks)
#pragma unroll
      for (int m = 0; m < 4; ++m)
#pragma unroll
        for (int n = 0; n < 2; ++n)
          acc[m + 4][n] = __builtin_amdgcn_mfma_f32_16x16x32_f16(
              af[2 * m + ks], b0v[2 * n + ks], acc[m + 4][n], 0, 0, 0);
    __builtin_amdgcn_s_setprio(0);
    __builtin_amdgcn_s_barrier();

    // ---- p3: quad(1,1) ta ; gate tb before trailing barrier
    if (!last) STAGE_A(ta + 2, 0);
    __builtin_amdgcn_s_barrier();
    __builtin_amdgcn_s_setprio(1);
#pragma unroll
    for (int ks = 0; ks < 2; ++ks)
#pragma unroll
      for (int m = 0; m < 4; ++m)
#pragma unroll
        for (int n = 0; n < 2; ++n)
          acc[m + 4][n + 2] = __builtin_amdgcn_mfma_f32_16x16x32_f16(
              af[2 * m + ks], b1v[2 * n + ks], acc[m + 4][n + 2], 0, 0, 0);
    __builtin_amdgcn_s_setprio(0);
    if (!last) asm volatile("s_waitcnt vmcnt(2)" ::: "memory");
    else       asm volatile("s_waitcnt vmcnt(0)" ::: "memory");
    __builtin_amdgcn_s_barrier();

    // ---- p4: quad(0,0) tb
    RD_A(buf1, 0, af); RD_B(buf1, 0, b0v);
    if (!last) STAGE_B(ta + 2, 0);
    __builtin_amdgcn_s_barrier();
    LGKM0;
    __builtin_amdgcn_s_setprio(1);
#pragma unroll
    for (int ks = 0; ks < 2; ++ks)
#pragma unroll
      for (int m = 0; m < 4; ++m)
#pragma unroll
        for (int n = 0; n < 2; ++n)
          acc[m][n] = __builtin_amdgcn_mfma_f32_16x16x32_f16(
              af[2 * m + ks], b0v[2 * n + ks], acc[m][n], 0, 0, 0);
    __builtin_amdgcn_s_setprio(0);
    __builtin_amdgcn_s_barrier();

    // ---- p5: quad(0,1) tb
    RD_B(buf1, 1, b1v);
    if (!last) STAGE_B(ta + 2, 1);
    __builtin_amdgcn_s_barrier();
    LGKM0;
    __builtin_amdgcn_s_setprio(1);
#pragma unroll
    for (int ks = 0; ks < 2; ++ks)
#pragma unroll
      for (int m = 0; m < 4; ++m)
#pragma unroll
        for (int n = 0; n < 2; ++n)
          acc[m][n + 2] = __builtin_amdgcn_mfma_f32_16x16x32_f16(
              af[2 * m + ks], b1v[2 * n + ks], acc[m][n + 2], 0, 0, 0);
    __builtin_amdgcn_s_setprio(0);
    __builtin_amdgcn_s_barrier();

    // ---- p6: quad(1,0) tb
    RD_A(buf1, 1, af);
    if (!last) STAGE_A(ta + 2, 1);
    __builtin_amdgcn_s_barrier();
    LGKM0;
    __builtin_amdgcn_s_setprio(1);
#pragma unroll
    for (int ks = 0; ks < 2; ++ks)
#pragma unroll
      for (int m = 0; m < 4; ++m)
#pragma unroll
        for (int n = 0; n < 2; ++n)
          acc[m + 4][n] = __builtin_amdgcn_mfma_f32_16x16x32_f16(
              af[2 * m + ks], b0v[2 * n + ks], acc[m + 4][n], 0, 0, 0);
    __builtin_amdgcn_s_setprio(0);
    __builtin_amdgcn_s_barrier();

    // ---- p7: quad(1,1) tb ; gate ta+2 before trailing barrier
    if (!last) STAGE_A(tb + 2, 0);
    __builtin_amdgcn_s_barrier();
    __builtin_amdgcn_s_setprio(1);
#pragma unroll
    for (int ks = 0; ks < 2; ++ks)
#pragma unroll
      for (int m = 0; m < 4; ++m)
#pragma unroll
        for (int n = 0; n < 2; ++n)
          acc[m + 4][n + 2] = __builtin_amdgcn_mfma_f32_16x16x32_f16(
              af[2 * m + ks], b1v[2 * n + ks], acc[m + 4][n + 2], 0, 0, 0);
    __builtin_amdgcn_s_setprio(0);
    if (!last) {
      asm volatile("s_waitcnt vmcnt(2)" ::: "memory");
    }
    __builtin_amdgcn_s_barrier();
  }

  const long cBase = (long)bz * cZ;
  const int rowBase = by * 256 + wm * 128;
  const int colBase = bx * 256 + wn * 64;

  if constexpr (EPI == 3) {
    u16* vT = (u16*)C;
#pragma unroll
    for (int m = 0; m < 8; ++m) {
      const long row0 = rowBase + m * 16 + (lane >> 4) * 4;
      const long bb2 = (row0 >> 11) * 4194304L + (row0 & 2047);
#pragma unroll
      for (int n = 0; n < 4; ++n) {
        const int col = colBase + n * 16 + l15;
        ushort4 h;
        h.x = f2h(acc[m][n][0]); h.y = f2h(acc[m][n][1]);
        h.z = f2h(acc[m][n][2]); h.w = f2h(acc[m][n][3]);
        *(ushort4*)(vT + bb2 + (long)col * 2048) = h;
      }
    }
  } else {
#pragma unroll
    for (int m = 0; m < 8; ++m) {
#pragma unroll
      for (int r = 0; r < 4; ++r) {
        const long row = rowBase + m * 16 + (lane >> 4) * 4 + r;
#pragma unroll
        for (int n = 0; n < 4; ++n) {
          const int col = colBase + n * 16 + l15;
          float v = acc[m][n][r];
          if constexpr (EPI == 0) {
            ((u16*)C)[cBase + row * ldc + col] = f2h(v);
          } else {
            v += bias[col];
            v = fmaxf(v, 0.0f);
            v += xres[row * (long)ldc + col];
            ((float*)C)[row * (long)ldc + col] = v;
          }
        }
      }
    }
  }
}

// ================================================================ gemm_bt
// m97-structure 128x128 GEMM (Plans B/C fallback; round-3 verified).
template <int EPI>
__global__ __launch_bounds__(256) void gemm_bt(
    const u16* __restrict__ A, const u16* __restrict__ B, void* __restrict__ C,
    int K, int lda, int ldb, int ldc,
    long aZ, long bZ, long cZ,
    const float* __restrict__ bias, const float* __restrict__ xres)
{
  __shared__ u16 sA[128 * 32];
  __shared__ u16 sB[128 * 32];
  const int tid = threadIdx.x;
  const int bz = blockIdx.z;
  const u16* Ab = A + (long)bz * aZ + (long)(blockIdx.y * 128) * lda;
  const u16* Bb = B + (long)bz * bZ + (long)(blockIdx.x * 128) * ldb;

  const int lane = tid & 63;
  const int wr = (tid >> 7) & 1;
  const int wc = (tid >> 6) & 1;
  const int l15 = lane & 15, l4 = lane >> 4;

  const int f0 = tid, f1 = tid + 256;
  const long ga0 = (long)(f0 >> 2) * lda + (f0 & 3) * 8;
  const long ga1 = (long)(f1 >> 2) * lda + (f1 & 3) * 8;
  const long gb0 = (long)(f0 >> 2) * ldb + (f0 & 3) * 8;
  const long gb1 = (long)(f1 >> 2) * ldb + (f1 & 3) * 8;
  u16* sAd0 = sA + (tid & ~63) * 8;
  u16* sAd1 = sA + 2048 + (tid & ~63) * 8;
  u16* sBd0 = sB + (tid & ~63) * 8;
  u16* sBd1 = sB + 2048 + (tid & ~63) * 8;

  f32x4 acc[4][4] = {};

  for (int k0 = 0; k0 < K; k0 += 32) {
    gload_lds16(Ab + ga0 + k0, sAd0);
    gload_lds16(Ab + ga1 + k0, sAd1);
    gload_lds16(Bb + gb0 + k0, sBd0);
    gload_lds16(Bb + gb1 + k0, sBd1);
    __syncthreads();
    f16x8 af[4], bf[4];
#pragma unroll
    for (int m = 0; m < 4; ++m)
      af[m] = *(const f16x8*)(sA + (wr * 64 + m * 16 + l15) * 32 + l4 * 8);
#pragma unroll
    for (int n = 0; n < 4; ++n)
      bf[n] = *(const f16x8*)(sB + (wc * 64 + n * 16 + l15) * 32 + l4 * 8);
#pragma unroll
    for (int m = 0; m < 4; ++m)
#pragma unroll
      for (int n = 0; n < 4; ++n)
        acc[m][n] = __builtin_amdgcn_mfma_f32_16x16x32_f16(af[m], bf[n], acc[m][n], 0, 0, 0);
    __syncthreads();
  }

  const long cBase = (long)bz * cZ;
  const int rowBase = blockIdx.y * 128 + wr * 64;
  const int colBase = blockIdx.x * 128 + wc * 64;

#pragma unroll
  for (int m = 0; m < 4; ++m) {
#pragma unroll
    for (int r = 0; r < 4; ++r) {
      const long row = rowBase + m * 16 + l4 * 4 + r;
#pragma unroll
      for (int n = 0; n < 4; ++n) {
        const int col = colBase + n * 16 + l15;
        float v = acc[m][n][r];
        if constexpr (EPI == 0) {
          ((u16*)C)[cBase + row * ldc + col] = f2h(v);
        } else if constexpr (EPI == 1) {
          ((float*)C)[cBase + row * ldc + col] = v;
        } else {
          v += bias[col];
          v = fmaxf(v, 0.0f);
          v += xres[row * (long)ldc + col];
          ((float*)C)[row * (long)ldc + col] = v;
        }
      }
    }
  }
}

// ------------------------------------------------------- softmax fp16 rows(2048)
__global__ __launch_bounds__(256) void softmax_rows16(u16* __restrict__ sc)
{
  const long row = blockIdx.x;
  u16* p = sc + row * 2048;
  const int tid = threadIdx.x;
  uint4 w = ((const uint4*)p)[tid];  // 8 fp16
  float e[8];
  e[0] = h2f(w.x & 0xffff); e[1] = h2f(w.x >> 16);
  e[2] = h2f(w.y & 0xffff); e[3] = h2f(w.y >> 16);
  e[4] = h2f(w.z & 0xffff); e[5] = h2f(w.z >> 16);
  e[6] = h2f(w.w & 0xffff); e[7] = h2f(w.w >> 16);
  float m = fmaxf(fmaxf(fmaxf(e[0], e[1]), fmaxf(e[2], e[3])),
                  fmaxf(fmaxf(e[4], e[5]), fmaxf(e[6], e[7])));
#pragma unroll
  for (int o = 32; o; o >>= 1) m = fmaxf(m, __shfl_xor(m, o));
  __shared__ float redm[4];
  if ((tid & 63) == 0) redm[tid >> 6] = m;
  __syncthreads();
  m = fmaxf(fmaxf(redm[0], redm[1]), fmaxf(redm[2], redm[3]));

  float s = 0.0f;
#pragma unroll
  for (int i = 0; i < 8; ++i) { e[i] = __expf(e[i] - m); s += e[i]; }
#pragma unroll
  for (int o = 32; o; o >>= 1) s += __shfl_xor(s, o);
  __shared__ float reds[4];
  if ((tid & 63) == 0) reds[tid >> 6] = s;
  __syncthreads();
  s = (reds[0] + reds[1]) + (reds[2] + reds[3]);
  const float inv = 1.0f / s;

  uint4 o;
  o.x = (uint32_t)f2h(e[0] * inv) | ((uint32_t)f2h(e[1] * inv) << 16);
  o.y = (uint32_t)f2h(e[2] * inv) | ((uint32_t)f2h(e[3] * inv) << 16);
  o.z = (uint32_t)f2h(e[4] * inv) | ((uint32_t)f2h(e[5] * inv) << 16);
  o.w = (uint32_t)f2h(e[6] * inv) | ((uint32_t)f2h(e[7] * inv) << 16);
  ((uint4*)p)[tid] = o;
}

// ------------------------------------------------------- softmax fp32 (B/C)
__global__ __launch_bounds__(256) void softmax_rows(float* __restrict__ scores)
{
  const long row = blockIdx.x;
  const float* src = scores + row * 2048;
  const int tid = threadIdx.x;
  float4 a = ((const float4*)src)[tid];
  float4 b = ((const float4*)src)[tid + 256];
  float m = fmaxf(fmaxf(fmaxf(a.x, a.y), fmaxf(a.z, a.w)),
                  fmaxf(fmaxf(b.x, b.y), fmaxf(b.z, b.w)));
#pragma unroll
  for (int o = 32; o; o >>= 1) m = fmaxf(m, __shfl_xor(m, o));
  __shared__ float redm[4];
  if ((tid & 63) == 0) redm[tid >> 6] = m;
  __syncthreads();
  m = fmaxf(fmaxf(redm[0], redm[1]), fmaxf(redm[2], redm[3]));

  float e[8];
  e[0] = __expf(a.x - m); e[1] = __expf(a.y - m);
  e[2] = __expf(a.z - m); e[3] = __expf(a.w - m);
  e[4] = __expf(b.x - m); e[5] = __expf(b.y - m);
  e[6] = __expf(b.z - m); e[7] = __expf(b.w - m);
  float s = ((e[0] + e[1]) + (e[2] + e[3])) + ((e[4] + e[5]) + (e[6] + e[7]));
#pragma unroll
  for (int o = 32; o; o >>= 1) s += __shfl_xor(s, o);
  __shared__ float reds[4];
  if ((tid & 63) == 0) reds[tid >> 6] = s;
  __syncthreads();
  s = (reds[0] + reds[1]) + (reds[2] + reds[3]);
  const float inv = 1.0f / s;

  u16* dst = (u16*)scores + row * 4096;
  uint2 w0, w1;
  w0.x = (uint32_t)f2h(e[0] * inv) | ((uint32_t)f2h(e[1] * inv) << 16);
  w0.y = (uint32_t)f2h(e[2] * inv) | ((uint32_t)f2h(e[3] * inv) << 16);
  w1.x = (uint32_t)f2h(e[4] * inv) | ((uint32_t)f2h(e[5] * inv) << 16);
  w1.y = (uint32_t)f2h(e[6] * inv) | ((uint32_t)f2h(e[7] * inv) << 16);
  ((uint2*)dst)[tid] = w0;
  ((uint2*)dst)[tid + 256] = w1;
}

// ------------------------------------------------------- layernorm (rows of 1024)
__global__ __launch_bounds__(256) void layernorm_rows(
    const float* __restrict__ y, const float* __restrict__ gamma,
    const float* __restrict__ beta, float* __restrict__ out)
{
  const long row = blockIdx.x;
  const int tid = threadIdx.x;
  float4 v = ((const float4*)(y + row * 1024))[tid];
  float s = (v.x + v.y) + (v.z + v.w);
  float q = (v.x * v.x + v.y * v.y) + (v.z * v.z + v.w * v.w);
#pragma unroll
  for (int o = 32; o; o >>= 1) { s += __shfl_xor(s, o); q += __shfl_xor(q, o); }
  __shared__ float rs[4], rq[4];
  if ((tid & 63) == 0) { rs[tid >> 6] = s; rq[tid >> 6] = q; }
  __syncthreads();
  s = (rs[0] + rs[1]) + (rs[2] + rs[3]);
  q = (rq[0] + rq[1]) + (rq[2] + rq[3]);
  const float mu = s * (1.0f / 1024.0f);
  const float var = q * (1.0f / 1024.0f) - mu * mu;
  const float rstd = rsqrtf(var + 1e-5f);
  float4 g = ((const float4*)gamma)[tid];
  float4 be = ((const float4*)beta)[tid];
  float4 o;
  o.x = (v.x - mu) * rstd * g.x + be.x;
  o.y = (v.y - mu) * rstd * g.y + be.y;
  o.z = (v.z - mu) * rstd * g.z + be.z;
  o.w = (v.w - mu) * rstd * g.w + be.w;
  __syncthreads();
  ((float4*)(out + row * 1024))[tid] = o;
}

// ------------------------------------------------------- fp32 -> fp16 (flat)
__global__ __launch_bounds__(256) void cvt_f32_f16(
    const float* __restrict__ in, u16* __restrict__ out, long n4)
{
  const long stride = (long)gridDim.x * 256;
  for (long i = (long)blockIdx.x * 256 + threadIdx.x; i < n4; i += stride) {
    float4 v = ((const float4*)in)[i];
    uint2 p;
    p.x = (uint32_t)f2h(v.x) | ((uint32_t)f2h(v.y) << 16);
    p.y = (uint32_t)f2h(v.z) | ((uint32_t)f2h(v.w) << 16);
    ((uint2*)out)[i] = p;
  }
}

// ------------------------------------------------------- transpose fp32->fp16
__global__ __launch_bounds__(256) void tw_f32(
    const float* __restrict__ in, u16* __restrict__ out, int R, int C)
{
  __shared__ float T[32][33];
  const int c0 = blockIdx.x * 32, r0 = blockIdx.y * 32;
  const int tx = threadIdx.x & 31, ty = threadIdx.x >> 5;
#pragma unroll
  for (int i = 0; i < 4; ++i)
    T[ty + i * 8][tx] = in[(long)(r0 + ty + i * 8) * C + c0 + tx];
  __syncthreads();
#pragma unroll
  for (int i = 0; i < 4; ++i)
    out[(long)(c0 + ty + i * 8) * R + r0 + tx] = f2h(T[tx][ty + i * 8]);
}

// ------------------------------------------------------- transpose u16 (per z)
__global__ __launch_bounds__(256) void transpose_u16(
    const u16* __restrict__ in, u16* __restrict__ out, int R, int C)
{
  __shared__ u16 T[32][33];
  const long zo = (long)blockIdx.z * R * C;
  const int c0 = blockIdx.x * 32, r0 = blockIdx.y * 32;
  const int tx = threadIdx.x & 31, ty = threadIdx.x >> 5;
#pragma unroll
  for (int i = 0; i < 4; ++i)
    T[ty + i * 8][tx] = in[zo + (long)(r0 + ty + i * 8) * C + c0 + tx];
  __syncthreads();
#pragma unroll
  for (int i = 0; i < 4; ++i)
    out[zo + (long)(c0 + ty + i * 8) * R + r0 + tx] = T[tx][ty + i * 8];
}

// ---------------------------------------------------------------- launch
extern "C" void kernel_launch(void* const* d_in, const int* in_sizes, int n_in,
                              void* d_out, int out_size, void* d_ws, size_t ws_size,
                              hipStream_t stream)
{
  const float* x     = (const float*)d_in[0];   // [16384,1024]
  const float* Wq    = (const float*)d_in[1];   // [1024,2048]
  const float* Wk    = (const float*)d_in[2];
  const float* Wv    = (const float*)d_in[3];
  const float* Wfc   = (const float*)d_in[4];   // [2048,1024]
  const float* bfc   = (const float*)d_in[5];   // [1024]
  const float* gamma = (const float*)d_in[6];
  const float* beta  = (const float*)d_in[7];
  float* out = (float*)d_out;

  char* ws = (char*)d_ws;

  u16* wqkvT = (u16*)(ws + 0);            // 3 x [2048][1024]
  u16* wfcT  = (u16*)(ws + 12582912);     //     [1024][2048]
  tw_f32<<<dim3(64, 32), 256, 0, stream>>>(Wq, wqkvT, 1024, 2048);
  tw_f32<<<dim3(64, 32), 256, 0, stream>>>(Wk, wqkvT + (long)2048 * 1024, 1024, 2048);
  tw_f32<<<dim3(64, 32), 256, 0, stream>>>(Wv, wqkvT + (long)2 * 2048 * 1024, 1024, 2048);
  tw_f32<<<dim3(32, 64), 256, 0, stream>>>(Wfc, wfcT, 2048, 1024);

  if (ws_size >= 251658240ULL) {
    // ---------------- Plan A ----------------
    u16*  q_   = (u16*)(ws + 16777216);     // [16384][2048] fp16 (later attx)
    u16*  k_   = (u16*)(ws + 83886080);     // [16384][2048] fp16
    u16*  vT   = (u16*)(ws + 150994944);    // [8][2048(dk)][2048(m)] fp16
    u16*  sc16 = (u16*)(ws + 218103808);    // 32 MiB: [8][1024][2048] fp16 scores
    u16*  xb   = sc16;                      // ALIAS: xb dies before sc16 born

    cvt_f32_f16<<<2048, 256, 0, stream>>>(x, xb, (long)16384 * 1024 / 4);

    // QKV: q,k (z = weight 0,1)
    gemm8x<0><<<dim3(8, 64, 2), 512, 0, stream>>>(
        xb, wqkvT, (void*)q_, 1024, 1024, 1024, 2048,
        0L, (long)2048 * 1024, (long)16384 * 2048, nullptr, nullptr);
    // V pre-transposed per batch
    gemm8x<3><<<dim3(8, 64, 1), 512, 0, stream>>>(
        xb, wqkvT + (long)2 * 2048 * 1024, (void*)vT, 1024, 1024, 1024, 2048,
        0L, 0L, 0L, nullptr, nullptr);

    // attention: 2 chunks of 1024 Q-rows x 8 batches, fp16 scores
    for (int c = 0; c < 2; ++c) {
      const u16* qc = q_ + (long)c * 1024 * 2048;
      gemm8x<0><<<dim3(8, 4, 8), 512, 0, stream>>>(
          qc, k_, (void*)sc16, 2048, 2048, 2048, 2048,
          (long)2048 * 2048, (long)2048 * 2048, (long)1024 * 2048, nullptr, nullptr);
      softmax_rows16<<<8192, 256, 0, stream>>>(sc16);
      gemm8x<0><<<dim3(8, 4, 8), 512, 0, stream>>>(
          sc16, vT, (void*)(q_ + (long)c * 1024 * 2048), 2048, 2048, 2048, 2048,
          (long)1024 * 2048, (long)2048 * 2048, (long)2048 * 2048, nullptr, nullptr);
    }

    // d_out = x + relu(attx @ Wfc + bfc)
    gemm8x<2><<<dim3(4, 64, 1), 512, 0, stream>>>(
        q_, wfcT, (void*)out, 2048, 2048, 2048, 1024,
        0L, 0L, 0L, bfc, x);
  } else if (ws_size >= 109051904ULL) {
    // ---------------- Plan B ----------------
    u16*  xb2 = (u16*)(ws + 16777216);
    u16*  q2  = (u16*)(ws + 25165824);
    u16*  k2  = q2 + (long)2 * 2048 * 2048;
    u16*  v2  = q2 + (long)4 * 2048 * 2048;
    float* sc2 = (float*)(ws + 75497472);
    u16*  vT2   = k2;
    u16*  attx2 = q2;

    for (int p = 0; p < 4; ++p) {
      const float* xp = x + (long)p * 4096 * 1024;
      cvt_f32_f16<<<1024, 256, 0, stream>>>(xp, xb2, (long)4096 * 1024 / 4);
      for (int b = 0; b < 2; ++b)
        gemm_bt<0><<<dim3(16, 16, 3), 256, 0, stream>>>(
            xb2 + (long)b * 2048 * 1024, wqkvT, (void*)(q2 + (long)b * 2048 * 2048),
            1024, 1024, 1024, 2048,
            0L, (long)2048 * 1024, (long)2 * 2048 * 2048, nullptr, nullptr);
      gemm_bt<1><<<dim3(16, 16, 2), 256, 0, stream>>>(
          q2, k2, (void*)sc2, 2048, 2048, 2048, 2048,
          (long)2048 * 2048, (long)2048 * 2048, (long)2048 * 2048, nullptr, nullptr);
      softmax_rows<<<4096, 256, 0, stream>>>(sc2);
      transpose_u16<<<dim3(64, 64, 2), 256, 0, stream>>>(v2, vT2, 2048, 2048);
      gemm_bt<0><<<dim3(16, 16, 2), 256, 0, stream>>>(
          (const u16*)sc2, vT2, (void*)attx2, 2048, 4096, 2048, 2048,
          (long)2048 * 4096, (long)2048 * 2048, (long)2048 * 2048, nullptr, nullptr);
      gemm_bt<2><<<dim3(8, 32, 1), 256, 0, stream>>>(
          attx2, wfcT, (void*)(out + (long)p * 4096 * 1024), 2048, 2048, 2048, 1024,
          0L, 0L, 0L, bfc, xp);
    }
  } else {
    // ---------------- Plan C ----------------
    u16*  xb_b   = (u16*)(ws + 16777216);
    u16*  qkv_b  = (u16*)(ws + 20971520);
    u16*  q_b    = qkv_b;
    u16*  k_b    = qkv_b + (long)2048 * 2048;
    u16*  v_b    = qkv_b + (long)2 * 2048 * 2048;
    float* sc_b  = (float*)(ws + 46137344);
    u16*  vT_b   = k_b;
    u16*  attx_b = q_b;

    for (int b = 0; b < 8; ++b) {
      const float* x_b = x + (long)b * 2048 * 1024;
      cvt_f32_f16<<<512, 256, 0, stream>>>(x_b, xb_b, (long)2048 * 1024 / 4);
      gemm_bt<0><<<dim3(16, 16, 3), 256, 0, stream>>>(
          xb_b, wqkvT, (void*)qkv_b, 1024, 1024, 1024, 2048,
          0L, (long)2048 * 1024, (long)2048 * 2048, nullptr, nullptr);
      gemm_bt<1><<<dim3(16, 16, 1), 256, 0, stream>>>(
          q_b, k_b, (void*)sc_b, 2048, 2048, 2048, 2048,
          0L, 0L, 0L, nullptr, nullptr);
      softmax_rows<<<2048, 256, 0, stream>>>(sc_b);
      transpose_u16<<<dim3(64, 64, 1), 256, 0, stream>>>(v_b, vT_b, 2048, 2048);
      gemm_bt<0><<<dim3(16, 16, 1), 256, 0, stream>>>(
          (const u16*)sc_b, vT_b, (void*)attx_b, 2048, 4096, 2048, 2048,
          0L, 0L, 0L, nullptr, nullptr);
      gemm_bt<2><<<dim3(8, 16, 1), 256, 0, stream>>>(
          attx_b, wfcT, (void*)(out + (long)b * 2048 * 1024), 2048, 2048, 2048, 1024,
          0L, 0L, 0L, bfc, x_b);
    }
  }

  layernorm_rows<<<16384, 256, 0, stream>>>(out, gamma, beta, out);
}

// Round 14
// 596.203 us; speedup vs baseline: 1.1707x; 1.1707x over previous
//
#include <hip/hip_runtime.h>
#include <stdint.h>

// Fused transformer block on MI355X (gfx950), fp16 MFMA pipeline.
// Plan A (ws >= 240 MiB): gemm8x — round-11 verified 8-phase schedule,
//   VERBATIM (256x256 tile, BK=64, 8 waves 2Mx4N, 2 LDS buffers, XOR swizzle,
//   stage map p0:A1(tb) p1:A0(ta+2) p2:B0(ta+2) p3:B1(ta+2) p4:A1(ta+2)
//   p5:A0(tb+2) p6:B0(tb+2) p7:B1(tb+2); 14-load prologue; steady gates all
//   vmcnt(10), last-iter 10,10,8,4,2,0).
//   r14 change (ONLY): EPI=3 epilogue stages the 256x256 output into LDS
//   (dead after the drained K-loop; [col][row] u16, row-stride 264) and
//   streams out coalesced 16B runs. Round 11 wrote per-lane 8B at 4KB
//   stride. Round 13's failure was a stage-map/gate mismatch (hybrid of
//   r11 gates with r12 stage order), NOT this epilogue.
// Attention: 2 chunks of 1024 Q-rows, fp16 scores, softmax in place.
// Plans B/C keep the round-3-verified m97-structure gemm_bt.

#define DEVI __device__ __forceinline__

typedef uint16_t u16;
typedef _Float16 f16x8 __attribute__((ext_vector_type(8)));
typedef float f32x4 __attribute__((ext_vector_type(4)));

DEVI u16 f2h(float f) {
  union { _Float16 h; u16 u; } v;
  v.h = (_Float16)f;
  return v.u;
}
DEVI float h2f(u16 x) {
  union { _Float16 h; u16 u; } v;
  v.u = x;
  return (float)v.h;
}

DEVI void gload_lds16(const void* g, void* lds) {
  __builtin_amdgcn_global_load_lds(
      (const __attribute__((address_space(1))) void*)g,
      (__attribute__((address_space(3))) void*)lds, 16, 0, 0);
}

#define GATE_S(N) do { asm volatile("s_waitcnt vmcnt(" #N ")" ::: "memory"); \
                       __builtin_amdgcn_s_barrier(); } while (0)
#define LGKM0 do { asm volatile("s_waitcnt lgkmcnt(0)" ::: "memory"); \
                   __builtin_amdgcn_sched_barrier(0); } while (0)

// ================================================================ gemm8x
// C[M,N] = A[M,K] * B^T, B row-major [N,K] (fp16). 512 thr = 8 waves (2Mx4N),
// per-wave 128x64 via 8x4 16x16x32 fragments. Tile 256x256, BK=64.
// EPI: 0 fp16; 2 fp32 bias+relu+residual; 3 fp16 V-transposed store (LDS xpose).
template <int EPI>
__global__ __launch_bounds__(512, 2) void gemm8x(
    const u16* __restrict__ A, const u16* __restrict__ B, void* __restrict__ C,
    int K, int lda, int ldb, int ldc,
    long aZ, long bZ, long cZ,
    const float* __restrict__ bias, const float* __restrict__ xres)
{
  // EPI==3 reuses LDS post-loop as [256 cols][264 rows-padded] u16 (135,168 B)
  __shared__ u16 lds[EPI == 3 ? 256 * 264 : 2 * 32768];
  char* ldsB = (char*)lds;
  const int tid = threadIdx.x;
  const int bz = blockIdx.z;

  // XCD-aware swizzle (gx*gy % 8 == 0 for all grids used)
  const int gx = gridDim.x;
  int fl = blockIdx.y * gx + blockIdx.x;
  const int cpx = (gx * gridDim.y) >> 3;
  fl = (fl & 7) * cpx + (fl >> 3);
  const int bx = fl % gx, by = fl / gx;

  const u16* Ab = A + (long)bz * aZ + (long)(by * 256) * lda;
  const u16* Bb = B + (long)bz * bZ + (long)(bx * 256) * ldb;

  const int wid = tid >> 6, lane = tid & 63;
  const int wm = wid >> 2, wn = wid & 3;  // 2M x 4N
  const int l15 = lane & 15;

  // staging maps (half h, chunk j): wave-uniform LDS dest + inverse-swizzled
  // per-lane global source. A-half h = rows [64h,+64) u [128+64h,+64);
  // B-half h = rows with bit5==h within each 64-row wn group.
  int aBase[2][2]; long aoff[2][2];
  int bBase[2][2]; long boff[2][2];
#pragma unroll
  for (int h = 0; h < 2; ++h) {
#pragma unroll
    for (int j = 0; j < 2; ++j) {
      const int s = wid * 2 + j;  // 0..15
      int rs = (s < 8) ? (64 * h + s * 8) : (128 + 64 * h + (s - 8) * 8);
      aBase[h][j] = rs * 128;
      {
        const int d = rs * 128 + lane * 16;
        const int dl = d ^ (((d >> 7) & 7) << 4);
        aoff[h][j] = (long)(dl >> 7) * (lda * 2) + (dl & 127);
      }
      rs = 64 * (s >> 2) + 32 * h + (s & 3) * 8;
      bBase[h][j] = 32768 + rs * 128;
      {
        const int d = rs * 128 + lane * 16;
        const int dl = d ^ (((d >> 7) & 7) << 4);
        boff[h][j] = (long)(dl >> 7) * (ldb * 2) + (dl & 127);
      }
    }
  }

  const int swz = (lane & 7) << 4;
  const int ko0 = ((lane >> 4) * 16) ^ swz;
  const int ko1 = (64 + (lane >> 4) * 16) ^ swz;

  f32x4 acc[8][4] = {};

  auto STAGE_A = [&](int t, int h) {
    char* dst = ldsB + (t & 1) * 65536;
    const long kB = (long)t * 128;
#pragma unroll
    for (int j = 0; j < 2; ++j)
      gload_lds16((const char*)Ab + aoff[h][j] + kB, dst + aBase[h][j]);
  };
  auto STAGE_B = [&](int t, int h) {
    char* dst = ldsB + (t & 1) * 65536;
    const long kB = (long)t * 128;
#pragma unroll
    for (int j = 0; j < 2; ++j)
      gload_lds16((const char*)Bb + boff[h][j] + kB, dst + bBase[h][j]);
  };
  auto RD_A = [&](const char* base, int mh, f16x8* dst) {
#pragma unroll
    for (int m = 0; m < 4; ++m) {
      const char* r = base + (wm * 128 + (mh * 4 + m) * 16 + l15) * 128;
      dst[2 * m] = *(const f16x8*)(r + ko0);
      dst[2 * m + 1] = *(const f16x8*)(r + ko1);
    }
  };
  auto RD_B = [&](const char* base, int nh, f16x8* dst) {
#pragma unroll
    for (int n = 0; n < 2; ++n) {
      const char* r = base + 32768 + (wn * 64 + (nh * 2 + n) * 16 + l15) * 128;
      dst[2 * n] = *(const f16x8*)(r + ko0);
      dst[2 * n + 1] = *(const f16x8*)(r + ko1);
    }
  };

  const int NT = K >> 6;       // even (K multiple of 128)
  const int NI = NT >> 1;
  const char* buf0 = ldsB;
  const char* buf1 = ldsB + 65536;

  // prologue = "iter -1" stages p1..p7: A0,B0,B1,A1(t0), A0,B0,B1(t1)
  STAGE_A(0, 0); STAGE_B(0, 0); STAGE_B(0, 1); STAGE_A(0, 1);
  STAGE_A(1, 0); STAGE_B(1, 0); STAGE_B(1, 1);

  for (int i = 0; i < NI; ++i) {
    const bool last = (i + 1 == NI);
    const int ta = 2 * i, tb = 2 * i + 1;
    f16x8 af[8], b0v[4], b1v[4];

    // ---- p0: quad(0,0) ta
    GATE_S(10);
    RD_A(buf0, 0, af); RD_B(buf0, 0, b0v);
    STAGE_A(tb, 1);
    LGKM0;
    __builtin_amdgcn_s_setprio(1);
#pragma unroll
    for (int ks = 0; ks < 2; ++ks)
#pragma unroll
      for (int m = 0; m < 4; ++m)
#pragma unroll
        for (int n = 0; n < 2; ++n)
          acc[m][n] = __builtin_amdgcn_mfma_f32_16x16x32_f16(
              af[2 * m + ks], b0v[2 * n + ks], acc[m][n], 0, 0, 0);
    __builtin_amdgcn_s_setprio(0);
    __builtin_amdgcn_s_barrier();

    // ---- p1: quad(0,1) ta
    GATE_S(10);
    RD_B(buf0, 1, b1v);
    if (!last) STAGE_A(ta + 2, 0);
    LGKM0;
    __builtin_amdgcn_s_setprio(1);
#pragma unroll
    for (int ks = 0; ks < 2; ++ks)
#pragma unroll
      for (int m = 0; m < 4; ++m)
#pragma unroll
        for (int n = 0; n < 2; ++n)
          acc[m][n + 2] = __builtin_amdgcn_mfma_f32_16x16x32_f16(
              af[2 * m + ks], b1v[2 * n + ks], acc[m][n + 2], 0, 0, 0);
    __builtin_amdgcn_s_setprio(0);
    __builtin_amdgcn_s_barrier();

    // ---- p2: quad(1,0) ta
    if (!last) GATE_S(10); else GATE_S(8);
    RD_A(buf0, 1, af);
    if (!last) STAGE_B(ta + 2, 0);
    LGKM0;
    __builtin_amdgcn_s_setprio(1);
#pragma unroll
    for (int ks = 0; ks < 2; ++ks)
#pragma unroll
      for (int m = 0; m < 4; ++m)
#pragma unroll
        for (int n = 0; n < 2; ++n)
          acc[m + 4][n] = __builtin_amdgcn_mfma_f32_16x16x32_f16(
              af[2 * m + ks], b0v[2 * n + ks], acc[m + 4][n], 0, 0, 0);
    __builtin_amdgcn_s_setprio(0);
    __builtin_amdgcn_s_barrier();

    // ---- p3: quad(1,1) ta (no gate, no reads)
    if (!last) STAGE_B(ta + 2, 1);
    __builtin_amdgcn_s_setprio(1);
#pragma unroll
    for (int ks = 0; ks < 2; ++ks)
#pragma unroll
      for (int m = 0; m < 4; ++m)
#pragma unroll
        for (int n = 0; n < 2; ++n)
          acc[m + 4][n + 2] = __builtin_amdgcn_mfma_f32_16x16x32_f16(
              af[2 * m + ks], b1v[2 * n + ks], acc[m + 4][n + 2], 0, 0, 0);
    __builtin_amdgcn_s_setprio(0);
    __builtin_amdgcn_s_barrier();

    // ---- p4: quad(0,0) tb
    if (!last) GATE_S(10); else GATE_S(4);
    RD_A(buf1, 0, af); RD_B(buf1, 0, b0v);
    if (!last) STAGE_A(ta + 2, 1);
    LGKM0;
    __builtin_amdgcn_s_setprio(1);
#pragma unroll
    for (int ks = 0; ks < 2; ++ks)
#pragma unroll
      for (int m = 0; m < 4; ++m)
#pragma unroll
        for (int n = 0; n < 2; ++n)
          acc[m][n] = __builtin_amdgcn_mfma_f32_16x16x32_f16(
              af[2 * m + ks], b0v[2 * n + ks], acc[m][n], 0, 0, 0);
    __builtin_amdgcn_s_setprio(0);
    __builtin_amdgcn_s_barrier();

    // ---- p5: quad(0,1) tb
    if (!last) GATE_S(10); else GATE_S(2);
    RD_B(buf1, 1, b1v);
    if (!last) STAGE_A(tb + 2, 0);
    LGKM0;
    __builtin_amdgcn_s_setprio(1);
#pragma unroll
    for (int ks = 0; ks < 2; ++ks)
#pragma unroll
      for (int m = 0; m < 4; ++m)
#pragma unroll
        for (int n = 0; n < 2; ++n)
          acc[m][n + 2] = __builtin_amdgcn_mfma_f32_16x16x32_f16(
              af[2 * m + ks], b1v[2 * n + ks], acc[m][n + 2], 0, 0, 0);
    __builtin_amdgcn_s_setprio(0);
    __builtin_amdgcn_s_barrier();

    // ---- p6: quad(1,0) tb
    if (!last) GATE_S(10); else GATE_S(0);
    RD_A(buf1, 1, af);
    if (!last) STAGE_B(tb + 2, 0);
    LGKM0;
    __builtin_amdgcn_s_setprio(1);
#pragma unroll
    for (int ks = 0; ks < 2; ++ks)
#pragma unroll
      for (int m = 0; m < 4; ++m)
#pragma unroll
        for (int n = 0; n < 2; ++n)
          acc[m + 4][n] = __builtin_amdgcn_mfma_f32_16x16x32_f16(
              af[2 * m + ks], b0v[2 * n + ks], acc[m + 4][n], 0, 0, 0);
    __builtin_amdgcn_s_setprio(0);
    __builtin_amdgcn_s_barrier();

    // ---- p7: quad(1,1) tb (no gate, no reads)
    if (!last) STAGE_B(tb + 2, 1);
    __builtin_amdgcn_s_setprio(1);
#pragma unroll
    for (int ks = 0; ks < 2; ++ks)
#pragma unroll
      for (int m = 0; m < 4; ++m)
#pragma unroll
        for (int n = 0; n < 2; ++n)
          acc[m + 4][n + 2] = __builtin_amdgcn_mfma_f32_16x16x32_f16(
              af[2 * m + ks], b1v[2 * n + ks], acc[m + 4][n + 2], 0, 0, 0);
    __builtin_amdgcn_s_setprio(0);
    __builtin_amdgcn_s_barrier();
  }

  const long cBase = (long)bz * cZ;
  const int rowBase = by * 256 + wm * 128;
  const int colBase = bx * 256 + wn * 64;

  if constexpr (EPI == 3) {
    // r14: coalesced V-transposed store via LDS transpose.
    // Pipeline LDS is dead here (last-iter gates drained vmcnt to 0 at p6,
    // and the final p7 barrier synchronized all waves).
    u16* ldsT = (u16*)ldsB;  // [col 0..255][row 0..255], row-stride 264
#pragma unroll
    for (int m = 0; m < 8; ++m) {
      const int row0 = wm * 128 + m * 16 + (lane >> 4) * 4;
#pragma unroll
      for (int n = 0; n < 4; ++n) {
        const int colL = wn * 64 + n * 16 + l15;
        ushort4 h;
        h.x = f2h(acc[m][n][0]); h.y = f2h(acc[m][n][1]);
        h.z = f2h(acc[m][n][2]); h.w = f2h(acc[m][n][3]);
        *(ushort4*)(ldsT + colL * 264 + row0) = h;
      }
    }
    __syncthreads();
    // Stream out: vT[(r>>11)*4194304 + (r&2047) + colG*2048], fastest dim = r.
    u16* vT = (u16*)C;
    const int rowBlk = by * 256;  // 256-row tile never straddles a 2048 batch
    const long base2 = ((long)rowBlk >> 11) * 4194304L + (rowBlk & 2047);
#pragma unroll
    for (int p = 0; p < 16; ++p) {
      const int idx = tid + p * 512;     // 0..8191
      const int colL = idx >> 5;         // 0..255
      const int ch = idx & 31;           // 32 x 16B chunks per column
      uint4 v = *(const uint4*)(ldsT + colL * 264 + ch * 8);
      *(uint4*)(vT + base2 + (long)(bx * 256 + colL) * 2048 + ch * 8) = v;
    }
  } else {
#pragma unroll
    for (int m = 0; m < 8; ++m) {
#pragma unroll
      for (int r = 0; r < 4; ++r) {
        const long row = rowBase + m * 16 + (lane >> 4) * 4 + r;
#pragma unroll
        for (int n = 0; n < 4; ++n) {
          const int col = colBase + n * 16 + l15;
          float v = acc[m][n][r];
          if constexpr (EPI == 0) {
            ((u16*)C)[cBase + row * ldc + col] = f2h(v);
          } else {
            v += bias[col];
            v = fmaxf(v, 0.0f);
            v += xres[row * (long)ldc + col];
            ((float*)C)[row * (long)ldc + col] = v;
          }
        }
      }
    }
  }
}

// ================================================================ gemm_bt
// m97-structure 128x128 GEMM (Plans B/C fallback; round-3 verified).
template <int EPI>
__global__ __launch_bounds__(256) void gemm_bt(
    const u16* __restrict__ A, const u16* __restrict__ B, void* __restrict__ C,
    int K, int lda, int ldb, int ldc,
    long aZ, long bZ, long cZ,
    const float* __restrict__ bias, const float* __restrict__ xres)
{
  __shared__ u16 sA[128 * 32];
  __shared__ u16 sB[128 * 32];
  const int tid = threadIdx.x;
  const int bz = blockIdx.z;
  const u16* Ab = A + (long)bz * aZ + (long)(blockIdx.y * 128) * lda;
  const u16* Bb = B + (long)bz * bZ + (long)(blockIdx.x * 128) * ldb;

  const int lane = tid & 63;
  const int wr = (tid >> 7) & 1;
  const int wc = (tid >> 6) & 1;
  const int l15 = lane & 15, l4 = lane >> 4;

  const int f0 = tid, f1 = tid + 256;
  const long ga0 = (long)(f0 >> 2) * lda + (f0 & 3) * 8;
  const long ga1 = (long)(f1 >> 2) * lda + (f1 & 3) * 8;
  const long gb0 = (long)(f0 >> 2) * ldb + (f0 & 3) * 8;
  const long gb1 = (long)(f1 >> 2) * ldb + (f1 & 3) * 8;
  u16* sAd0 = sA + (tid & ~63) * 8;
  u16* sAd1 = sA + 2048 + (tid & ~63) * 8;
  u16* sBd0 = sB + (tid & ~63) * 8;
  u16* sBd1 = sB + 2048 + (tid & ~63) * 8;

  f32x4 acc[4][4] = {};

  for (int k0 = 0; k0 < K; k0 += 32) {
    gload_lds16(Ab + ga0 + k0, sAd0);
    gload_lds16(Ab + ga1 + k0, sAd1);
    gload_lds16(Bb + gb0 + k0, sBd0);
    gload_lds16(Bb + gb1 + k0, sBd1);
    __syncthreads();
    f16x8 af[4], bf[4];
#pragma unroll
    for (int m = 0; m < 4; ++m)
      af[m] = *(const f16x8*)(sA + (wr * 64 + m * 16 + l15) * 32 + l4 * 8);
#pragma unroll
    for (int n = 0; n < 4; ++n)
      bf[n] = *(const f16x8*)(sB + (wc * 64 + n * 16 + l15) * 32 + l4 * 8);
#pragma unroll
    for (int m = 0; m < 4; ++m)
#pragma unroll
      for (int n = 0; n < 4; ++n)
        acc[m][n] = __builtin_amdgcn_mfma_f32_16x16x32_f16(af[m], bf[n], acc[m][n], 0, 0, 0);
    __syncthreads();
  }

  const long cBase = (long)bz * cZ;
  const int rowBase = blockIdx.y * 128 + wr * 64;
  const int colBase = blockIdx.x * 128 + wc * 64;

#pragma unroll
  for (int m = 0; m < 4; ++m) {
#pragma unroll
    for (int r = 0; r < 4; ++r) {
      const long row = rowBase + m * 16 + l4 * 4 + r;
#pragma unroll
      for (int n = 0; n < 4; ++n) {
        const int col = colBase + n * 16 + l15;
        float v = acc[m][n][r];
        if constexpr (EPI == 0) {
          ((u16*)C)[cBase + row * ldc + col] = f2h(v);
        } else if constexpr (EPI == 1) {
          ((float*)C)[cBase + row * ldc + col] = v;
        } else {
          v += bias[col];
          v = fmaxf(v, 0.0f);
          v += xres[row * (long)ldc + col];
          ((float*)C)[row * (long)ldc + col] = v;
        }
      }
    }
  }
}

// ------------------------------------------------------- softmax fp16 rows(2048)
__global__ __launch_bounds__(256) void softmax_rows16(u16* __restrict__ sc)
{
  const long row = blockIdx.x;
  u16* p = sc + row * 2048;
  const int tid = threadIdx.x;
  uint4 w = ((const uint4*)p)[tid];  // 8 fp16
  float e[8];
  e[0] = h2f(w.x & 0xffff); e[1] = h2f(w.x >> 16);
  e[2] = h2f(w.y & 0xffff); e[3] = h2f(w.y >> 16);
  e[4] = h2f(w.z & 0xffff); e[5] = h2f(w.z >> 16);
  e[6] = h2f(w.w & 0xffff); e[7] = h2f(w.w >> 16);
  float m = fmaxf(fmaxf(fmaxf(e[0], e[1]), fmaxf(e[2], e[3])),
                  fmaxf(fmaxf(e[4], e[5]), fmaxf(e[6], e[7])));
#pragma unroll
  for (int o = 32; o; o >>= 1) m = fmaxf(m, __shfl_xor(m, o));
  __shared__ float redm[4];
  if ((tid & 63) == 0) redm[tid >> 6] = m;
  __syncthreads();
  m = fmaxf(fmaxf(redm[0], redm[1]), fmaxf(redm[2], redm[3]));

  float s = 0.0f;
#pragma unroll
  for (int i = 0; i < 8; ++i) { e[i] = __expf(e[i] - m); s += e[i]; }
#pragma unroll
  for (int o = 32; o; o >>= 1) s += __shfl_xor(s, o);
  __shared__ float reds[4];
  if ((tid & 63) == 0) reds[tid >> 6] = s;
  __syncthreads();
  s = (reds[0] + reds[1]) + (reds[2] + reds[3]);
  const float inv = 1.0f / s;

  uint4 o;
  o.x = (uint32_t)f2h(e[0] * inv) | ((uint32_t)f2h(e[1] * inv) << 16);
  o.y = (uint32_t)f2h(e[2] * inv) | ((uint32_t)f2h(e[3] * inv) << 16);
  o.z = (uint32_t)f2h(e[4] * inv) | ((uint32_t)f2h(e[5] * inv) << 16);
  o.w = (uint32_t)f2h(e[6] * inv) | ((uint32_t)f2h(e[7] * inv) << 16);
  ((uint4*)p)[tid] = o;
}

// ------------------------------------------------------- softmax fp32 (B/C)
__global__ __launch_bounds__(256) void softmax_rows(float* __restrict__ scores)
{
  const long row = blockIdx.x;
  const float* src = scores + row * 2048;
  const int tid = threadIdx.x;
  float4 a = ((const float4*)src)[tid];
  float4 b = ((const float4*)src)[tid + 256];
  float m = fmaxf(fmaxf(fmaxf(a.x, a.y), fmaxf(a.z, a.w)),
                  fmaxf(fmaxf(b.x, b.y), fmaxf(b.z, b.w)));
#pragma unroll
  for (int o = 32; o; o >>= 1) m = fmaxf(m, __shfl_xor(m, o));
  __shared__ float redm[4];
  if ((tid & 63) == 0) redm[tid >> 6] = m;
  __syncthreads();
  m = fmaxf(fmaxf(redm[0], redm[1]), fmaxf(redm[2], redm[3]));

  float e[8];
  e[0] = __expf(a.x - m); e[1] = __expf(a.y - m);
  e[2] = __expf(a.z - m); e[3] = __expf(a.w - m);
  e[4] = __expf(b.x - m); e[5] = __expf(b.y - m);
  e[6] = __expf(b.z - m); e[7] = __expf(b.w - m);
  float s = ((e[0] + e[1]) + (e[2] + e[3])) + ((e[4] + e[5]) + (e[6] + e[7]));
#pragma unroll
  for (int o = 32; o; o >>= 1) s += __shfl_xor(s, o);
  __shared__ float reds[4];
  if ((tid & 63) == 0) reds[tid >> 6] = s;
  __syncthreads();
  s = (reds[0] + reds[1]) + (reds[2] + reds[3]);
  const float inv = 1.0f / s;

  u16* dst = (u16*)scores + row * 4096;
  uint2 w0, w1;
  w0.x = (uint32_t)f2h(e[0] * inv) | ((uint32_t)f2h(e[1] * inv) << 16);
  w0.y = (uint32_t)f2h(e[2] * inv) | ((uint32_t)f2h(e[3] * inv) << 16);
  w1.x = (uint32_t)f2h(e[4] * inv) | ((uint32_t)f2h(e[5] * inv) << 16);
  w1.y = (uint32_t)f2h(e[6] * inv) | ((uint32_t)f2h(e[7] * inv) << 16);
  ((uint2*)dst)[tid] = w0;
  ((uint2*)dst)[tid + 256] = w1;
}

// ------------------------------------------------------- layernorm (rows of 1024)
__global__ __launch_bounds__(256) void layernorm_rows(
    const float* __restrict__ y, const float* __restrict__ gamma,
    const float* __restrict__ beta, float* __restrict__ out)
{
  const long row = blockIdx.x;
  const int tid = threadIdx.x;
  float4 v = ((const float4*)(y + row * 1024))[tid];
  float s = (v.x + v.y) + (v.z + v.w);
  float q = (v.x * v.x + v.y * v.y) + (v.z * v.z + v.w * v.w);
#pragma unroll
  for (int o = 32; o; o >>= 1) { s += __shfl_xor(s, o); q += __shfl_xor(q, o); }
  __shared__ float rs[4], rq[4];
  if ((tid & 63) == 0) { rs[tid >> 6] = s; rq[tid >> 6] = q; }
  __syncthreads();
  s = (rs[0] + rs[1]) + (rs[2] + rs[3]);
  q = (rq[0] + rq[1]) + (rq[2] + rq[3]);
  const float mu = s * (1.0f / 1024.0f);
  const float var = q * (1.0f / 1024.0f) - mu * mu;
  const float rstd = rsqrtf(var + 1e-5f);
  float4 g = ((const float4*)gamma)[tid];
  float4 be = ((const float4*)beta)[tid];
  float4 o;
  o.x = (v.x - mu) * rstd * g.x + be.x;
  o.y = (v.y - mu) * rstd * g.y + be.y;
  o.z = (v.z - mu) * rstd * g.z + be.z;
  o.w = (v.w - mu) * rstd * g.w + be.w;
  __syncthreads();
  ((float4*)(out + row * 1024))[tid] = o;
}

// ------------------------------------------------------- fp32 -> fp16 (flat)
__global__ __launch_bounds__(256) void cvt_f32_f16(
    const float* __restrict__ in, u16* __restrict__ out, long n4)
{
  const long stride = (long)gridDim.x * 256;
  for (long i = (long)blockIdx.x * 256 + threadIdx.x; i < n4; i += stride) {
    float4 v = ((const float4*)in)[i];
    uint2 p;
    p.x = (uint32_t)f2h(v.x) | ((uint32_t)f2h(v.y) << 16);
    p.y = (uint32_t)f2h(v.z) | ((uint32_t)f2h(v.w) << 16);
    ((uint2*)out)[i] = p;
  }
}

// ------------------------------------------------------- transpose fp32->fp16
__global__ __launch_bounds__(256) void tw_f32(
    const float* __restrict__ in, u16* __restrict__ out, int R, int C)
{
  __shared__ float T[32][33];
  const int c0 = blockIdx.x * 32, r0 = blockIdx.y * 32;
  const int tx = threadIdx.x & 31, ty = threadIdx.x >> 5;
#pragma unroll
  for (int i = 0; i < 4; ++i)
    T[ty + i * 8][tx] = in[(long)(r0 + ty + i * 8) * C + c0 + tx];
  __syncthreads();
#pragma unroll
  for (int i = 0; i < 4; ++i)
    out[(long)(c0 + ty + i * 8) * R + r0 + tx] = f2h(T[tx][ty + i * 8]);
}

// ------------------------------------------------------- transpose u16 (per z)
__global__ __launch_bounds__(256) void transpose_u16(
    const u16* __restrict__ in, u16* __restrict__ out, int R, int C)
{
  __shared__ u16 T[32][33];
  const long zo = (long)blockIdx.z * R * C;
  const int c0 = blockIdx.x * 32, r0 = blockIdx.y * 32;
  const int tx = threadIdx.x & 31, ty = threadIdx.x >> 5;
#pragma unroll
  for (int i = 0; i < 4; ++i)
    T[ty + i * 8][tx] = in[zo + (long)(r0 + ty + i * 8) * C + c0 + tx];
  __syncthreads();
#pragma unroll
  for (int i = 0; i < 4; ++i)
    out[zo + (long)(c0 + ty + i * 8) * R + r0 + tx] = T[tx][ty + i * 8];
}

// ---------------------------------------------------------------- launch
extern "C" void kernel_launch(void* const* d_in, const int* in_sizes, int n_in,
                              void* d_out, int out_size, void* d_ws, size_t ws_size,
                              hipStream_t stream)
{
  const float* x     = (const float*)d_in[0];   // [16384,1024]
  const float* Wq    = (const float*)d_in[1];   // [1024,2048]
  const float* Wk    = (const float*)d_in[2];
  const float* Wv    = (const float*)d_in[3];
  const float* Wfc   = (const float*)d_in[4];   // [2048,1024]
  const float* bfc   = (const float*)d_in[5];   // [1024]
  const float* gamma = (const float*)d_in[6];
  const float* beta  = (const float*)d_in[7];
  float* out = (float*)d_out;

  char* ws = (char*)d_ws;

  u16* wqkvT = (u16*)(ws + 0);            // 3 x [2048][1024]
  u16* wfcT  = (u16*)(ws + 12582912);     //     [1024][2048]
  tw_f32<<<dim3(64, 32), 256, 0, stream>>>(Wq, wqkvT, 1024, 2048);
  tw_f32<<<dim3(64, 32), 256, 0, stream>>>(Wk, wqkvT + (long)2048 * 1024, 1024, 2048);
  tw_f32<<<dim3(64, 32), 256, 0, stream>>>(Wv, wqkvT + (long)2 * 2048 * 1024, 1024, 2048);
  tw_f32<<<dim3(32, 64), 256, 0, stream>>>(Wfc, wfcT, 2048, 1024);

  if (ws_size >= 251658240ULL) {
    // ---------------- Plan A ----------------
    u16*  q_   = (u16*)(ws + 16777216);     // [16384][2048] fp16 (later attx)
    u16*  k_   = (u16*)(ws + 83886080);     // [16384][2048] fp16
    u16*  vT   = (u16*)(ws + 150994944);    // [8][2048(dk)][2048(m)] fp16
    u16*  sc16 = (u16*)(ws + 218103808);    // 32 MiB: [8][1024][2048] fp16 scores
    u16*  xb   = sc16;                      // ALIAS: xb dies before sc16 born

    cvt_f32_f16<<<2048, 256, 0, stream>>>(x, xb, (long)16384 * 1024 / 4);

    // QKV: q,k (z = weight 0,1)
    gemm8x<0><<<dim3(8, 64, 2), 512, 0, stream>>>(
        xb, wqkvT, (void*)q_, 1024, 1024, 1024, 2048,
        0L, (long)2048 * 1024, (long)16384 * 2048, nullptr, nullptr);
    // V pre-transposed per batch (coalesced LDS-transpose store)
    gemm8x<3><<<dim3(8, 64, 1), 512, 0, stream>>>(
        xb, wqkvT + (long)2 * 2048 * 1024, (void*)vT, 1024, 1024, 1024, 2048,
        0L, 0L, 0L, nullptr, nullptr);

    // attention: 2 chunks of 1024 Q-rows x 8 batches, fp16 scores
    for (int c = 0; c < 2; ++c) {
      const u16* qc = q_ + (long)c * 1024 * 2048;
      gemm8x<0><<<dim3(8, 4, 8), 512, 0, stream>>>(
          qc, k_, (void*)sc16, 2048, 2048, 2048, 2048,
          (long)2048 * 2048, (long)2048 * 2048, (long)1024 * 2048, nullptr, nullptr);
      softmax_rows16<<<8192, 256, 0, stream>>>(sc16);
      gemm8x<0><<<dim3(8, 4, 8), 512, 0, stream>>>(
          sc16, vT, (void*)(q_ + (long)c * 1024 * 2048), 2048, 2048, 2048, 2048,
          (long)1024 * 2048, (long)2048 * 2048, (long)2048 * 2048, nullptr, nullptr);
    }

    // d_out = x + relu(attx @ Wfc + bfc)
    gemm8x<2><<<dim3(4, 64, 1), 512, 0, stream>>>(
        q_, wfcT, (void*)out, 2048, 2048, 2048, 1024,
        0L, 0L, 0L, bfc, x);
  } else if (ws_size >= 109051904ULL) {
    // ---------------- Plan B ----------------
    u16*  xb2 = (u16*)(ws + 16777216);
    u16*  q2  = (u16*)(ws + 25165824);
    u16*  k2  = q2 + (long)2 * 2048 * 2048;
    u16*  v2  = q2 + (long)4 * 2048 * 2048;
    float* sc2 = (float*)(ws + 75497472);
    u16*  vT2   = k2;
    u16*  attx2 = q2;

    for (int p = 0; p < 4; ++p) {
      const float* xp = x + (long)p * 4096 * 1024;
      cvt_f32_f16<<<1024, 256, 0, stream>>>(xp, xb2, (long)4096 * 1024 / 4);
      for (int b = 0; b < 2; ++b)
        gemm_bt<0><<<dim3(16, 16, 3), 256, 0, stream>>>(
            xb2 + (long)b * 2048 * 1024, wqkvT, (void*)(q2 + (long)b * 2048 * 2048),
            1024, 1024, 1024, 2048,
            0L, (long)2048 * 1024, (long)2 * 2048 * 2048, nullptr, nullptr);
      gemm_bt<1><<<dim3(16, 16, 2), 256, 0, stream>>>(
          q2, k2, (void*)sc2, 2048, 2048, 2048, 2048,
          (long)2048 * 2048, (long)2048 * 2048, (long)2048 * 2048, nullptr, nullptr);
      softmax_rows<<<4096, 256, 0, stream>>>(sc2);
      transpose_u16<<<dim3(64, 64, 2), 256, 0, stream>>>(v2, vT2, 2048, 2048);
      gemm_bt<0><<<dim3(16, 16, 2), 256, 0, stream>>>(
          (const u16*)sc2, vT2, (void*)attx2, 2048, 4096, 2048, 2048,
          (long)2048 * 4096, (long)2048 * 2048, (long)2048 * 2048, nullptr, nullptr);
      gemm_bt<2><<<dim3(8, 32, 1), 256, 0, stream>>>(
          attx2, wfcT, (void*)(out + (long)p * 4096 * 1024), 2048, 2048, 2048, 1024,
          0L, 0L, 0L, bfc, xp);
    }
  } else {
    // ---------------- Plan C ----------------
    u16*  xb_b   = (u16*)(ws + 16777216);
    u16*  qkv_b  = (u16*)(ws + 20971520);
    u16*  q_b    = qkv_b;
    u16*  k_b    = qkv_b + (long)2048 * 2048;
    u16*  v_b    = qkv_b + (long)2 * 2048 * 2048;
    float* sc_b  = (float*)(ws + 46137344);
    u16*  vT_b   = k_b;
    u16*  attx_b = q_b;

    for (int b = 0; b < 8; ++b) {
      const float* x_b = x + (long)b * 2048 * 1024;
      cvt_f32_f16<<<512, 256, 0, stream>>>(x_b, xb_b, (long)2048 * 1024 / 4);
      gemm_bt<0><<<dim3(16, 16, 3), 256, 0, stream>>>(
          xb_b, wqkvT, (void*)qkv_b, 1024, 1024, 1024, 2048,
          0L, (long)2048 * 1024, (long)2048 * 2048, nullptr, nullptr);
      gemm_bt<1><<<dim3(16, 16, 1), 256, 0, stream>>>(
          q_b, k_b, (void*)sc_b, 2048, 2048, 2048, 2048,
          0L, 0L, 0L, nullptr, nullptr);
      softmax_rows<<<2048, 256, 0, stream>>>(sc_b);
      transpose_u16<<<dim3(64, 64, 1), 256, 0, stream>>>(v_b, vT_b, 2048, 2048);
      gemm_bt<0><<<dim3(16, 16, 1), 256, 0, stream>>>(
          (const u16*)sc_b, vT_b, (void*)attx_b, 2048, 4096, 2048, 2048,
          0L, 0L, 0L, nullptr, nullptr);
      gemm_bt<2><<<dim3(8, 16, 1), 256, 0, stream>>>(
          attx_b, wfcT, (void*)(out + (long)b * 2048 * 1024), 2048, 2048, 2048, 1024,
          0L, 0L, 0L, bfc, x_b);
    }
  }

  layernorm_rows<<<16384, 256, 0, stream>>>(out, gamma, beta, out);
}

// Round 15
// 590.988 us; speedup vs baseline: 1.1811x; 1.0088x over previous
//
#include <hip/hip_runtime.h>
#include <stdint.h>

// Fused transformer block on MI355X (gfx950), fp16 MFMA pipeline.
// Plan A (ws >= 240 MiB): gemm8x — r15: round-14 schedule with trailing
//   barriers DELETED (one barrier per phase, m201's form). Stage map, gates,
//   reads, prologue, epilogues byte-identical to r14. Safety re-proven:
//   every LDS region's re-stage is >=1 leading-barrier after its readers'
//   lgkmcnt(0) drain; vmcnt ledger unchanged (same issue order).
//   Phases: p0-p2,p4-p6 = [vmcnt-gate+bar; reads; stage; lgkm0; MFMA];
//           p3,p7       = [bar; stage; MFMA].
// Attention: 2 chunks of 1024 Q-rows, fp16 scores, softmax in place.
// Plans B/C keep the round-3-verified m97-structure gemm_bt.

#define DEVI __device__ __forceinline__

typedef uint16_t u16;
typedef _Float16 f16x8 __attribute__((ext_vector_type(8)));
typedef float f32x4 __attribute__((ext_vector_type(4)));

DEVI u16 f2h(float f) {
  union { _Float16 h; u16 u; } v;
  v.h = (_Float16)f;
  return v.u;
}
DEVI float h2f(u16 x) {
  union { _Float16 h; u16 u; } v;
  v.u = x;
  return (float)v.h;
}

DEVI void gload_lds16(const void* g, void* lds) {
  __builtin_amdgcn_global_load_lds(
      (const __attribute__((address_space(1))) void*)g,
      (__attribute__((address_space(3))) void*)lds, 16, 0, 0);
}

#define GATE_S(N) do { asm volatile("s_waitcnt vmcnt(" #N ")" ::: "memory"); \
                       __builtin_amdgcn_s_barrier(); } while (0)
#define LGKM0 do { asm volatile("s_waitcnt lgkmcnt(0)" ::: "memory"); \
                   __builtin_amdgcn_sched_barrier(0); } while (0)

// ================================================================ gemm8x
// C[M,N] = A[M,K] * B^T, B row-major [N,K] (fp16). 512 thr = 8 waves (2Mx4N),
// per-wave 128x64 via 8x4 16x16x32 fragments. Tile 256x256, BK=64.
// EPI: 0 fp16; 2 fp32 bias+relu+residual; 3 fp16 V-transposed store (LDS xpose).
template <int EPI>
__global__ __launch_bounds__(512, 2) void gemm8x(
    const u16* __restrict__ A, const u16* __restrict__ B, void* __restrict__ C,
    int K, int lda, int ldb, int ldc,
    long aZ, long bZ, long cZ,
    const float* __restrict__ bias, const float* __restrict__ xres)
{
  // EPI==3 reuses LDS post-loop as [256 cols][264 rows-padded] u16 (135,168 B)
  __shared__ u16 lds[EPI == 3 ? 256 * 264 : 2 * 32768];
  char* ldsB = (char*)lds;
  const int tid = threadIdx.x;
  const int bz = blockIdx.z;

  // XCD-aware swizzle (gx*gy % 8 == 0 for all grids used)
  const int gx = gridDim.x;
  int fl = blockIdx.y * gx + blockIdx.x;
  const int cpx = (gx * gridDim.y) >> 3;
  fl = (fl & 7) * cpx + (fl >> 3);
  const int bx = fl % gx, by = fl / gx;

  const u16* Ab = A + (long)bz * aZ + (long)(by * 256) * lda;
  const u16* Bb = B + (long)bz * bZ + (long)(bx * 256) * ldb;

  const int wid = tid >> 6, lane = tid & 63;
  const int wm = wid >> 2, wn = wid & 3;  // 2M x 4N
  const int l15 = lane & 15;

  // staging maps (half h, chunk j): wave-uniform LDS dest + inverse-swizzled
  // per-lane global source. A-half h = rows [64h,+64) u [128+64h,+64);
  // B-half h = rows with bit5==h within each 64-row wn group.
  int aBase[2][2]; long aoff[2][2];
  int bBase[2][2]; long boff[2][2];
#pragma unroll
  for (int h = 0; h < 2; ++h) {
#pragma unroll
    for (int j = 0; j < 2; ++j) {
      const int s = wid * 2 + j;  // 0..15
      int rs = (s < 8) ? (64 * h + s * 8) : (128 + 64 * h + (s - 8) * 8);
      aBase[h][j] = rs * 128;
      {
        const int d = rs * 128 + lane * 16;
        const int dl = d ^ (((d >> 7) & 7) << 4);
        aoff[h][j] = (long)(dl >> 7) * (lda * 2) + (dl & 127);
      }
      rs = 64 * (s >> 2) + 32 * h + (s & 3) * 8;
      bBase[h][j] = 32768 + rs * 128;
      {
        const int d = rs * 128 + lane * 16;
        const int dl = d ^ (((d >> 7) & 7) << 4);
        boff[h][j] = (long)(dl >> 7) * (ldb * 2) + (dl & 127);
      }
    }
  }

  const int swz = (lane & 7) << 4;
  const int ko0 = ((lane >> 4) * 16) ^ swz;
  const int ko1 = (64 + (lane >> 4) * 16) ^ swz;

  f32x4 acc[8][4] = {};

  auto STAGE_A = [&](int t, int h) {
    char* dst = ldsB + (t & 1) * 65536;
    const long kB = (long)t * 128;
#pragma unroll
    for (int j = 0; j < 2; ++j)
      gload_lds16((const char*)Ab + aoff[h][j] + kB, dst + aBase[h][j]);
  };
  auto STAGE_B = [&](int t, int h) {
    char* dst = ldsB + (t & 1) * 65536;
    const long kB = (long)t * 128;
#pragma unroll
    for (int j = 0; j < 2; ++j)
      gload_lds16((const char*)Bb + boff[h][j] + kB, dst + bBase[h][j]);
  };
  auto RD_A = [&](const char* base, int mh, f16x8* dst) {
#pragma unroll
    for (int m = 0; m < 4; ++m) {
      const char* r = base + (wm * 128 + (mh * 4 + m) * 16 + l15) * 128;
      dst[2 * m] = *(const f16x8*)(r + ko0);
      dst[2 * m + 1] = *(const f16x8*)(r + ko1);
    }
  };
  auto RD_B = [&](const char* base, int nh, f16x8* dst) {
#pragma unroll
    for (int n = 0; n < 2; ++n) {
      const char* r = base + 32768 + (wn * 64 + (nh * 2 + n) * 16 + l15) * 128;
      dst[2 * n] = *(const f16x8*)(r + ko0);
      dst[2 * n + 1] = *(const f16x8*)(r + ko1);
    }
  };

  const int NT = K >> 6;       // even (K multiple of 128)
  const int NI = NT >> 1;
  const char* buf0 = ldsB;
  const char* buf1 = ldsB + 65536;

  // prologue = "iter -1" stages p1..p7: A0,B0,B1,A1(t0), A0,B0,B1(t1)
  STAGE_A(0, 0); STAGE_B(0, 0); STAGE_B(0, 1); STAGE_A(0, 1);
  STAGE_A(1, 0); STAGE_B(1, 0); STAGE_B(1, 1);

  for (int i = 0; i < NI; ++i) {
    const bool last = (i + 1 == NI);
    const int ta = 2 * i, tb = 2 * i + 1;
    f16x8 af[8], b0v[4], b1v[4];

    // ---- p0: quad(0,0) ta
    GATE_S(10);
    RD_A(buf0, 0, af); RD_B(buf0, 0, b0v);
    STAGE_A(tb, 1);
    LGKM0;
    __builtin_amdgcn_s_setprio(1);
#pragma unroll
    for (int ks = 0; ks < 2; ++ks)
#pragma unroll
      for (int m = 0; m < 4; ++m)
#pragma unroll
        for (int n = 0; n < 2; ++n)
          acc[m][n] = __builtin_amdgcn_mfma_f32_16x16x32_f16(
              af[2 * m + ks], b0v[2 * n + ks], acc[m][n], 0, 0, 0);
    __builtin_amdgcn_s_setprio(0);

    // ---- p1: quad(0,1) ta
    GATE_S(10);
    RD_B(buf0, 1, b1v);
    if (!last) STAGE_A(ta + 2, 0);
    LGKM0;
    __builtin_amdgcn_s_setprio(1);
#pragma unroll
    for (int ks = 0; ks < 2; ++ks)
#pragma unroll
      for (int m = 0; m < 4; ++m)
#pragma unroll
        for (int n = 0; n < 2; ++n)
          acc[m][n + 2] = __builtin_amdgcn_mfma_f32_16x16x32_f16(
              af[2 * m + ks], b1v[2 * n + ks], acc[m][n + 2], 0, 0, 0);
    __builtin_amdgcn_s_setprio(0);

    // ---- p2: quad(1,0) ta
    if (!last) GATE_S(10); else GATE_S(8);
    RD_A(buf0, 1, af);
    if (!last) STAGE_B(ta + 2, 0);
    LGKM0;
    __builtin_amdgcn_s_setprio(1);
#pragma unroll
    for (int ks = 0; ks < 2; ++ks)
#pragma unroll
      for (int m = 0; m < 4; ++m)
#pragma unroll
        for (int n = 0; n < 2; ++n)
          acc[m + 4][n] = __builtin_amdgcn_mfma_f32_16x16x32_f16(
              af[2 * m + ks], b0v[2 * n + ks], acc[m + 4][n], 0, 0, 0);
    __builtin_amdgcn_s_setprio(0);

    // ---- p3: quad(1,1) ta (leading barrier; no gate, no reads)
    __builtin_amdgcn_s_barrier();
    if (!last) STAGE_B(ta + 2, 1);
    __builtin_amdgcn_s_setprio(1);
#pragma unroll
    for (int ks = 0; ks < 2; ++ks)
#pragma unroll
      for (int m = 0; m < 4; ++m)
#pragma unroll
        for (int n = 0; n < 2; ++n)
          acc[m + 4][n + 2] = __builtin_amdgcn_mfma_f32_16x16x32_f16(
              af[2 * m + ks], b1v[2 * n + ks], acc[m + 4][n + 2], 0, 0, 0);
    __builtin_amdgcn_s_setprio(0);

    // ---- p4: quad(0,0) tb
    if (!last) GATE_S(10); else GATE_S(4);
    RD_A(buf1, 0, af); RD_B(buf1, 0, b0v);
    if (!last) STAGE_A(ta + 2, 1);
    LGKM0;
    __builtin_amdgcn_s_setprio(1);
#pragma unroll
    for (int ks = 0; ks < 2; ++ks)
#pragma unroll
      for (int m = 0; m < 4; ++m)
#pragma unroll
        for (int n = 0; n < 2; ++n)
          acc[m][n] = __builtin_amdgcn_mfma_f32_16x16x32_f16(
              af[2 * m + ks], b0v[2 * n + ks], acc[m][n], 0, 0, 0);
    __builtin_amdgcn_s_setprio(0);

    // ---- p5: quad(0,1) tb
    if (!last) GATE_S(10); else GATE_S(2);
    RD_B(buf1, 1, b1v);
    if (!last) STAGE_A(tb + 2, 0);
    LGKM0;
    __builtin_amdgcn_s_setprio(1);
#pragma unroll
    for (int ks = 0; ks < 2; ++ks)
#pragma unroll
      for (int m = 0; m < 4; ++m)
#pragma unroll
        for (int n = 0; n < 2; ++n)
          acc[m][n + 2] = __builtin_amdgcn_mfma_f32_16x16x32_f16(
              af[2 * m + ks], b1v[2 * n + ks], acc[m][n + 2], 0, 0, 0);
    __builtin_amdgcn_s_setprio(0);

    // ---- p6: quad(1,0) tb
    if (!last) GATE_S(10); else GATE_S(0);
    RD_A(buf1, 1, af);
    if (!last) STAGE_B(tb + 2, 0);
    LGKM0;
    __builtin_amdgcn_s_setprio(1);
#pragma unroll
    for (int ks = 0; ks < 2; ++ks)
#pragma unroll
      for (int m = 0; m < 4; ++m)
#pragma unroll
        for (int n = 0; n < 2; ++n)
          acc[m + 4][n] = __builtin_amdgcn_mfma_f32_16x16x32_f16(
              af[2 * m + ks], b0v[2 * n + ks], acc[m + 4][n], 0, 0, 0);
    __builtin_amdgcn_s_setprio(0);

    // ---- p7: quad(1,1) tb (leading barrier; no gate, no reads)
    __builtin_amdgcn_s_barrier();
    if (!last) STAGE_B(tb + 2, 1);
    __builtin_amdgcn_s_setprio(1);
#pragma unroll
    for (int ks = 0; ks < 2; ++ks)
#pragma unroll
      for (int m = 0; m < 4; ++m)
#pragma unroll
        for (int n = 0; n < 2; ++n)
          acc[m + 4][n + 2] = __builtin_amdgcn_mfma_f32_16x16x32_f16(
              af[2 * m + ks], b1v[2 * n + ks], acc[m + 4][n + 2], 0, 0, 0);
    __builtin_amdgcn_s_setprio(0);
  }

  const long cBase = (long)bz * cZ;
  const int rowBase = by * 256 + wm * 128;
  const int colBase = bx * 256 + wn * 64;

  if constexpr (EPI == 3) {
    // Coalesced V-transposed store via LDS transpose. Safe: any wave here
    // passed barrier(p7 last iter), which laggards reach only after their
    // p6 lgkmcnt(0) drained all LDS reads; vmcnt drained by p6 gate (0).
    u16* ldsT = (u16*)ldsB;  // [col 0..255][row 0..255], row-stride 264
#pragma unroll
    for (int m = 0; m < 8; ++m) {
      const int row0 = wm * 128 + m * 16 + (lane >> 4) * 4;
#pragma unroll
      for (int n = 0; n < 4; ++n) {
        const int colL = wn * 64 + n * 16 + l15;
        ushort4 h;
        h.x = f2h(acc[m][n][0]); h.y = f2h(acc[m][n][1]);
        h.z = f2h(acc[m][n][2]); h.w = f2h(acc[m][n][3]);
        *(ushort4*)(ldsT + colL * 264 + row0) = h;
      }
    }
    __syncthreads();
    u16* vT = (u16*)C;
    const int rowBlk = by * 256;  // 256-row tile never straddles a 2048 batch
    const long base2 = ((long)rowBlk >> 11) * 4194304L + (rowBlk & 2047);
#pragma unroll
    for (int p = 0; p < 16; ++p) {
      const int idx = tid + p * 512;     // 0..8191
      const int colL = idx >> 5;         // 0..255
      const int ch = idx & 31;           // 32 x 16B chunks per column
      uint4 v = *(const uint4*)(ldsT + colL * 264 + ch * 8);
      *(uint4*)(vT + base2 + (long)(bx * 256 + colL) * 2048 + ch * 8) = v;
    }
  } else {
#pragma unroll
    for (int m = 0; m < 8; ++m) {
#pragma unroll
      for (int r = 0; r < 4; ++r) {
        const long row = rowBase + m * 16 + (lane >> 4) * 4 + r;
#pragma unroll
        for (int n = 0; n < 4; ++n) {
          const int col = colBase + n * 16 + l15;
          float v = acc[m][n][r];
          if constexpr (EPI == 0) {
            ((u16*)C)[cBase + row * ldc + col] = f2h(v);
          } else {
            v += bias[col];
            v = fmaxf(v, 0.0f);
            v += xres[row * (long)ldc + col];
            ((float*)C)[row * (long)ldc + col] = v;
          }
        }
      }
    }
  }
}

// ================================================================ gemm_bt
// m97-structure 128x128 GEMM (Plans B/C fallback; round-3 verified).
template <int EPI>
__global__ __launch_bounds__(256) void gemm_bt(
    const u16* __restrict__ A, const u16* __restrict__ B, void* __restrict__ C,
    int K, int lda, int ldb, int ldc,
    long aZ, long bZ, long cZ,
    const float* __restrict__ bias, const float* __restrict__ xres)
{
  __shared__ u16 sA[128 * 32];
  __shared__ u16 sB[128 * 32];
  const int tid = threadIdx.x;
  const int bz = blockIdx.z;
  const u16* Ab = A + (long)bz * aZ + (long)(blockIdx.y * 128) * lda;
  const u16* Bb = B + (long)bz * bZ + (long)(blockIdx.x * 128) * ldb;

  const int lane = tid & 63;
  const int wr = (tid >> 7) & 1;
  const int wc = (tid >> 6) & 1;
  const int l15 = lane & 15, l4 = lane >> 4;

  const int f0 = tid, f1 = tid + 256;
  const long ga0 = (long)(f0 >> 2) * lda + (f0 & 3) * 8;
  const long ga1 = (long)(f1 >> 2) * lda + (f1 & 3) * 8;
  const long gb0 = (long)(f0 >> 2) * ldb + (f0 & 3) * 8;
  const long gb1 = (long)(f1 >> 2) * ldb + (f1 & 3) * 8;
  u16* sAd0 = sA + (tid & ~63) * 8;
  u16* sAd1 = sA + 2048 + (tid & ~63) * 8;
  u16* sBd0 = sB + (tid & ~63) * 8;
  u16* sBd1 = sB + 2048 + (tid & ~63) * 8;

  f32x4 acc[4][4] = {};

  for (int k0 = 0; k0 < K; k0 += 32) {
    gload_lds16(Ab + ga0 + k0, sAd0);
    gload_lds16(Ab + ga1 + k0, sAd1);
    gload_lds16(Bb + gb0 + k0, sBd0);
    gload_lds16(Bb + gb1 + k0, sBd1);
    __syncthreads();
    f16x8 af[4], bf[4];
#pragma unroll
    for (int m = 0; m < 4; ++m)
      af[m] = *(const f16x8*)(sA + (wr * 64 + m * 16 + l15) * 32 + l4 * 8);
#pragma unroll
    for (int n = 0; n < 4; ++n)
      bf[n] = *(const f16x8*)(sB + (wc * 64 + n * 16 + l15) * 32 + l4 * 8);
#pragma unroll
    for (int m = 0; m < 4; ++m)
#pragma unroll
      for (int n = 0; n < 4; ++n)
        acc[m][n] = __builtin_amdgcn_mfma_f32_16x16x32_f16(af[m], bf[n], acc[m][n], 0, 0, 0);
    __syncthreads();
  }

  const long cBase = (long)bz * cZ;
  const int rowBase = blockIdx.y * 128 + wr * 64;
  const int colBase = blockIdx.x * 128 + wc * 64;

#pragma unroll
  for (int m = 0; m < 4; ++m) {
#pragma unroll
    for (int r = 0; r < 4; ++r) {
      const long row = rowBase + m * 16 + l4 * 4 + r;
#pragma unroll
      for (int n = 0; n < 4; ++n) {
        const int col = colBase + n * 16 + l15;
        float v = acc[m][n][r];
        if constexpr (EPI == 0) {
          ((u16*)C)[cBase + row * ldc + col] = f2h(v);
        } else if constexpr (EPI == 1) {
          ((float*)C)[cBase + row * ldc + col] = v;
        } else {
          v += bias[col];
          v = fmaxf(v, 0.0f);
          v += xres[row * (long)ldc + col];
          ((float*)C)[row * (long)ldc + col] = v;
        }
      }
    }
  }
}

// ------------------------------------------------------- softmax fp16 rows(2048)
__global__ __launch_bounds__(256) void softmax_rows16(u16* __restrict__ sc)
{
  const long row = blockIdx.x;
  u16* p = sc + row * 2048;
  const int tid = threadIdx.x;
  uint4 w = ((const uint4*)p)[tid];  // 8 fp16
  float e[8];
  e[0] = h2f(w.x & 0xffff); e[1] = h2f(w.x >> 16);
  e[2] = h2f(w.y & 0xffff); e[3] = h2f(w.y >> 16);
  e[4] = h2f(w.z & 0xffff); e[5] = h2f(w.z >> 16);
  e[6] = h2f(w.w & 0xffff); e[7] = h2f(w.w >> 16);
  float m = fmaxf(fmaxf(fmaxf(e[0], e[1]), fmaxf(e[2], e[3])),
                  fmaxf(fmaxf(e[4], e[5]), fmaxf(e[6], e[7])));
#pragma unroll
  for (int o = 32; o; o >>= 1) m = fmaxf(m, __shfl_xor(m, o));
  __shared__ float redm[4];
  if ((tid & 63) == 0) redm[tid >> 6] = m;
  __syncthreads();
  m = fmaxf(fmaxf(redm[0], redm[1]), fmaxf(redm[2], redm[3]));

  float s = 0.0f;
#pragma unroll
  for (int i = 0; i < 8; ++i) { e[i] = __expf(e[i] - m); s += e[i]; }
#pragma unroll
  for (int o = 32; o; o >>= 1) s += __shfl_xor(s, o);
  __shared__ float reds[4];
  if ((tid & 63) == 0) reds[tid >> 6] = s;
  __syncthreads();
  s = (reds[0] + reds[1]) + (reds[2] + reds[3]);
  const float inv = 1.0f / s;

  uint4 o;
  o.x = (uint32_t)f2h(e[0] * inv) | ((uint32_t)f2h(e[1] * inv) << 16);
  o.y = (uint32_t)f2h(e[2] * inv) | ((uint32_t)f2h(e[3] * inv) << 16);
  o.z = (uint32_t)f2h(e[4] * inv) | ((uint32_t)f2h(e[5] * inv) << 16);
  o.w = (uint32_t)f2h(e[6] * inv) | ((uint32_t)f2h(e[7] * inv) << 16);
  ((uint4*)p)[tid] = o;
}

// ------------------------------------------------------- softmax fp32 (B/C)
__global__ __launch_bounds__(256) void softmax_rows(float* __restrict__ scores)
{
  const long row = blockIdx.x;
  const float* src = scores + row * 2048;
  const int tid = threadIdx.x;
  float4 a = ((const float4*)src)[tid];
  float4 b = ((const float4*)src)[tid + 256];
  float m = fmaxf(fmaxf(fmaxf(a.x, a.y), fmaxf(a.z, a.w)),
                  fmaxf(fmaxf(b.x, b.y), fmaxf(b.z, b.w)));
#pragma unroll
  for (int o = 32; o; o >>= 1) m = fmaxf(m, __shfl_xor(m, o));
  __shared__ float redm[4];
  if ((tid & 63) == 0) redm[tid >> 6] = m;
  __syncthreads();
  m = fmaxf(fmaxf(redm[0], redm[1]), fmaxf(redm[2], redm[3]));

  float e[8];
  e[0] = __expf(a.x - m); e[1] = __expf(a.y - m);
  e[2] = __expf(a.z - m); e[3] = __expf(a.w - m);
  e[4] = __expf(b.x - m); e[5] = __expf(b.y - m);
  e[6] = __expf(b.z - m); e[7] = __expf(b.w - m);
  float s = ((e[0] + e[1]) + (e[2] + e[3])) + ((e[4] + e[5]) + (e[6] + e[7]));
#pragma unroll
  for (int o = 32; o; o >>= 1) s += __shfl_xor(s, o);
  __shared__ float reds[4];
  if ((tid & 63) == 0) reds[tid >> 6] = s;
  __syncthreads();
  s = (reds[0] + reds[1]) + (reds[2] + reds[3]);
  const float inv = 1.0f / s;

  u16* dst = (u16*)scores + row * 4096;
  uint2 w0, w1;
  w0.x = (uint32_t)f2h(e[0] * inv) | ((uint32_t)f2h(e[1] * inv) << 16);
  w0.y = (uint32_t)f2h(e[2] * inv) | ((uint32_t)f2h(e[3] * inv) << 16);
  w1.x = (uint32_t)f2h(e[4] * inv) | ((uint32_t)f2h(e[5] * inv) << 16);
  w1.y = (uint32_t)f2h(e[6] * inv) | ((uint32_t)f2h(e[7] * inv) << 16);
  ((uint2*)dst)[tid] = w0;
  ((uint2*)dst)[tid + 256] = w1;
}

// ------------------------------------------------------- layernorm (rows of 1024)
__global__ __launch_bounds__(256) void layernorm_rows(
    const float* __restrict__ y, const float* __restrict__ gamma,
    const float* __restrict__ beta, float* __restrict__ out)
{
  const long row = blockIdx.x;
  const int tid = threadIdx.x;
  float4 v = ((const float4*)(y + row * 1024))[tid];
  float s = (v.x + v.y) + (v.z + v.w);
  float q = (v.x * v.x + v.y * v.y) + (v.z * v.z + v.w * v.w);
#pragma unroll
  for (int o = 32; o; o >>= 1) { s += __shfl_xor(s, o); q += __shfl_xor(q, o); }
  __shared__ float rs[4], rq[4];
  if ((tid & 63) == 0) { rs[tid >> 6] = s; rq[tid >> 6] = q; }
  __syncthreads();
  s = (rs[0] + rs[1]) + (rs[2] + rs[3]);
  q = (rq[0] + rq[1]) + (rq[2] + rq[3]);
  const float mu = s * (1.0f / 1024.0f);
  const float var = q * (1.0f / 1024.0f) - mu * mu;
  const float rstd = rsqrtf(var + 1e-5f);
  float4 g = ((const float4*)gamma)[tid];
  float4 be = ((const float4*)beta)[tid];
  float4 o;
  o.x = (v.x - mu) * rstd * g.x + be.x;
  o.y = (v.y - mu) * rstd * g.y + be.y;
  o.z = (v.z - mu) * rstd * g.z + be.z;
  o.w = (v.w - mu) * rstd * g.w + be.w;
  __syncthreads();
  ((float4*)(out + row * 1024))[tid] = o;
}

// ------------------------------------------------------- fp32 -> fp16 (flat)
__global__ __launch_bounds__(256) void cvt_f32_f16(
    const float* __restrict__ in, u16* __restrict__ out, long n4)
{
  const long stride = (long)gridDim.x * 256;
  for (long i = (long)blockIdx.x * 256 + threadIdx.x; i < n4; i += stride) {
    float4 v = ((const float4*)in)[i];
    uint2 p;
    p.x = (uint32_t)f2h(v.x) | ((uint32_t)f2h(v.y) << 16);
    p.y = (uint32_t)f2h(v.z) | ((uint32_t)f2h(v.w) << 16);
    ((uint2*)out)[i] = p;
  }
}

// ------------------------------------------------------- transpose fp32->fp16
__global__ __launch_bounds__(256) void tw_f32(
    const float* __restrict__ in, u16* __restrict__ out, int R, int C)
{
  __shared__ float T[32][33];
  const int c0 = blockIdx.x * 32, r0 = blockIdx.y * 32;
  const int tx = threadIdx.x & 31, ty = threadIdx.x >> 5;
#pragma unroll
  for (int i = 0; i < 4; ++i)
    T[ty + i * 8][tx] = in[(long)(r0 + ty + i * 8) * C + c0 + tx];
  __syncthreads();
#pragma unroll
  for (int i = 0; i < 4; ++i)
    out[(long)(c0 + ty + i * 8) * R + r0 + tx] = f2h(T[tx][ty + i * 8]);
}

// ------------------------------------------------------- transpose u16 (per z)
__global__ __launch_bounds__(256) void transpose_u16(
    const u16* __restrict__ in, u16* __restrict__ out, int R, int C)
{
  __shared__ u16 T[32][33];
  const long zo = (long)blockIdx.z * R * C;
  const int c0 = blockIdx.x * 32, r0 = blockIdx.y * 32;
  const int tx = threadIdx.x & 31, ty = threadIdx.x >> 5;
#pragma unroll
  for (int i = 0; i < 4; ++i)
    T[ty + i * 8][tx] = in[zo + (long)(r0 + ty + i * 8) * C + c0 + tx];
  __syncthreads();
#pragma unroll
  for (int i = 0; i < 4; ++i)
    out[zo + (long)(c0 + ty + i * 8) * R + r0 + tx] = T[tx][ty + i * 8];
}

// ---------------------------------------------------------------- launch
extern "C" void kernel_launch(void* const* d_in, const int* in_sizes, int n_in,
                              void* d_out, int out_size, void* d_ws, size_t ws_size,
                              hipStream_t stream)
{
  const float* x     = (const float*)d_in[0];   // [16384,1024]
  const float* Wq    = (const float*)d_in[1];   // [1024,2048]
  const float* Wk    = (const float*)d_in[2];
  const float* Wv    = (const float*)d_in[3];
  const float* Wfc   = (const float*)d_in[4];   // [2048,1024]
  const float* bfc   = (const float*)d_in[5];   // [1024]
  const float* gamma = (const float*)d_in[6];
  const float* beta  = (const float*)d_in[7];
  float* out = (float*)d_out;

  char* ws = (char*)d_ws;

  u16* wqkvT = (u16*)(ws + 0);            // 3 x [2048][1024]
  u16* wfcT  = (u16*)(ws + 12582912);     //     [1024][2048]
  tw_f32<<<dim3(64, 32), 256, 0, stream>>>(Wq, wqkvT, 1024, 2048);
  tw_f32<<<dim3(64, 32), 256, 0, stream>>>(Wk, wqkvT + (long)2048 * 1024, 1024, 2048);
  tw_f32<<<dim3(64, 32), 256, 0, stream>>>(Wv, wqkvT + (long)2 * 2048 * 1024, 1024, 2048);
  tw_f32<<<dim3(32, 64), 256, 0, stream>>>(Wfc, wfcT, 2048, 1024);

  if (ws_size >= 251658240ULL) {
    // ---------------- Plan A ----------------
    u16*  q_   = (u16*)(ws + 16777216);     // [16384][2048] fp16 (later attx)
    u16*  k_   = (u16*)(ws + 83886080);     // [16384][2048] fp16
    u16*  vT   = (u16*)(ws + 150994944);    // [8][2048(dk)][2048(m)] fp16
    u16*  sc16 = (u16*)(ws + 218103808);    // 32 MiB: [8][1024][2048] fp16 scores
    u16*  xb   = sc16;                      // ALIAS: xb dies before sc16 born

    cvt_f32_f16<<<2048, 256, 0, stream>>>(x, xb, (long)16384 * 1024 / 4);

    // QKV: q,k (z = weight 0,1)
    gemm8x<0><<<dim3(8, 64, 2), 512, 0, stream>>>(
        xb, wqkvT, (void*)q_, 1024, 1024, 1024, 2048,
        0L, (long)2048 * 1024, (long)16384 * 2048, nullptr, nullptr);
    // V pre-transposed per batch (coalesced LDS-transpose store)
    gemm8x<3><<<dim3(8, 64, 1), 512, 0, stream>>>(
        xb, wqkvT + (long)2 * 2048 * 1024, (void*)vT, 1024, 1024, 1024, 2048,
        0L, 0L, 0L, nullptr, nullptr);

    // attention: 2 chunks of 1024 Q-rows x 8 batches, fp16 scores
    for (int c = 0; c < 2; ++c) {
      const u16* qc = q_ + (long)c * 1024 * 2048;
      gemm8x<0><<<dim3(8, 4, 8), 512, 0, stream>>>(
          qc, k_, (void*)sc16, 2048, 2048, 2048, 2048,
          (long)2048 * 2048, (long)2048 * 2048, (long)1024 * 2048, nullptr, nullptr);
      softmax_rows16<<<8192, 256, 0, stream>>>(sc16);
      gemm8x<0><<<dim3(8, 4, 8), 512, 0, stream>>>(
          sc16, vT, (void*)(q_ + (long)c * 1024 * 2048), 2048, 2048, 2048, 2048,
          (long)1024 * 2048, (long)2048 * 2048, (long)2048 * 2048, nullptr, nullptr);
    }

    // d_out = x + relu(attx @ Wfc + bfc)
    gemm8x<2><<<dim3(4, 64, 1), 512, 0, stream>>>(
        q_, wfcT, (void*)out, 2048, 2048, 2048, 1024,
        0L, 0L, 0L, bfc, x);
  } else if (ws_size >= 109051904ULL) {
    // ---------------- Plan B ----------------
    u16*  xb2 = (u16*)(ws + 16777216);
    u16*  q2  = (u16*)(ws + 25165824);
    u16*  k2  = q2 + (long)2 * 2048 * 2048;
    u16*  v2  = q2 + (long)4 * 2048 * 2048;
    float* sc2 = (float*)(ws + 75497472);
    u16*  vT2   = k2;
    u16*  attx2 = q2;

    for (int p = 0; p < 4; ++p) {
      const float* xp = x + (long)p * 4096 * 1024;
      cvt_f32_f16<<<1024, 256, 0, stream>>>(xp, xb2, (long)4096 * 1024 / 4);
      for (int b = 0; b < 2; ++b)
        gemm_bt<0><<<dim3(16, 16, 3), 256, 0, stream>>>(
            xb2 + (long)b * 2048 * 1024, wqkvT, (void*)(q2 + (long)b * 2048 * 2048),
            1024, 1024, 1024, 2048,
            0L, (long)2048 * 1024, (long)2 * 2048 * 2048, nullptr, nullptr);
      gemm_bt<1><<<dim3(16, 16, 2), 256, 0, stream>>>(
          q2, k2, (void*)sc2, 2048, 2048, 2048, 2048,
          (long)2048 * 2048, (long)2048 * 2048, (long)2048 * 2048, nullptr, nullptr);
      softmax_rows<<<4096, 256, 0, stream>>>(sc2);
      transpose_u16<<<dim3(64, 64, 2), 256, 0, stream>>>(v2, vT2, 2048, 2048);
      gemm_bt<0><<<dim3(16, 16, 2), 256, 0, stream>>>(
          (const u16*)sc2, vT2, (void*)attx2, 2048, 4096, 2048, 2048,
          (long)2048 * 4096, (long)2048 * 2048, (long)2048 * 2048, nullptr, nullptr);
      gemm_bt<2><<<dim3(8, 32, 1), 256, 0, stream>>>(
          attx2, wfcT, (void*)(out + (long)p * 4096 * 1024), 2048, 2048, 2048, 1024,
          0L, 0L, 0L, bfc, xp);
    }
  } else {
    // ---------------- Plan C ----------------
    u16*  xb_b   = (u16*)(ws + 16777216);
    u16*  qkv_b  = (u16*)(ws + 20971520);
    u16*  q_b    = qkv_b;
    u16*  k_b    = qkv_b + (long)2048 * 2048;
    u16*  v_b    = qkv_b + (long)2 * 2048 * 2048;
    float* sc_b  = (float*)(ws + 46137344);
    u16*  vT_b   = k_b;
    u16*  attx_b = q_b;

    for (int b = 0; b < 8; ++b) {
      const float* x_b = x + (long)b * 2048 * 1024;
      cvt_f32_f16<<<512, 256, 0, stream>>>(x_b, xb_b, (long)2048 * 1024 / 4);
      gemm_bt<0><<<dim3(16, 16, 3), 256, 0, stream>>>(
          xb_b, wqkvT, (void*)qkv_b, 1024, 1024, 1024, 2048,
          0L, (long)2048 * 1024, (long)2048 * 2048, nullptr, nullptr);
      gemm_bt<1><<<dim3(16, 16, 1), 256, 0, stream>>>(
          q_b, k_b, (void*)sc_b, 2048, 2048, 2048, 2048,
          0L, 0L, 0L, nullptr, nullptr);
      softmax_rows<<<2048, 256, 0, stream>>>(sc_b);
      transpose_u16<<<dim3(64, 64, 1), 256, 0, stream>>>(v_b, vT_b, 2048, 2048);
      gemm_bt<0><<<dim3(16, 16, 1), 256, 0, stream>>>(
          (const u16*)sc_b, vT_b, (void*)attx_b, 2048, 4096, 2048, 2048,
          0L, 0L, 0L, nullptr, nullptr);
      gemm_bt<2><<<dim3(8, 16, 1), 256, 0, stream>>>(
          attx_b, wfcT, (void*)(out + (long)b * 2048 * 1024), 2048, 2048, 2048, 1024,
          0L, 0L, 0L, bfc, x_b);
    }
  }

  layernorm_rows<<<16384, 256, 0, stream>>>(out, gamma, beta, out);
}